// Round 4
// baseline (628.349 us; speedup 1.0000x reference)
//
#include <hip/hip_runtime.h>
#include <hip/hip_bf16.h>
#include <math.h>

#define HDIM 768
#define NHEAD 12
#define HEADD 64
#define FFDIM 3072
#define NEXP 4
#define SEQ 128
#define NB 64
#define QKVN 2304
#define MAXT 19   // max expert-grouped tiles of 4 samples: 16 + 3

typedef __attribute__((ext_vector_type(8))) _Float16 f16x8;
typedef __attribute__((ext_vector_type(4))) float f32x4;

__device__ __forceinline__ float gelu_tanh(float x) {
  float x3 = x * x * x;
  return 0.5f * x * (1.0f + tanhf(0.7978845608028654f * (x + 0.044715f * x3)));
}

__device__ __forceinline__ void gld_lds16(const void* g, void* l) {
  __builtin_amdgcn_global_load_lds(
      (const __attribute__((address_space(1))) unsigned int*)g,
      (__attribute__((address_space(3))) unsigned int*)l, 16, 0, 0);
}

// ---------------- routing ----------------------------------------------------
__global__ __launch_bounds__(256) void route_kernel(
    const float* __restrict__ hs, const float* __restrict__ centers,
    int* __restrict__ eid) {
  int b = blockIdx.x, t = threadIdx.x;
  __shared__ float hp[HDIM];
  __shared__ float dist[NEXP];
  const float* xb = hs + (size_t)b * SEQ * HDIM;
  for (int h = t; h < HDIM; h += 256) {
    float s = 0.f;
    for (int sq = 0; sq < SEQ; ++sq) s += xb[(size_t)sq * HDIM + h];
    hp[h] = s * (1.0f / SEQ);
  }
  if (t < NEXP) dist[t] = 0.f;
  __syncthreads();
  float pe[NEXP] = {0.f, 0.f, 0.f, 0.f};
  for (int h = t; h < HDIM; h += 256) {
    float v = hp[h];
#pragma unroll
    for (int e = 0; e < NEXP; ++e) {
      float d = v - centers[e * HDIM + h];
      pe[e] += d * d;
    }
  }
#pragma unroll
  for (int e = 0; e < NEXP; ++e) atomicAdd(&dist[e], pe[e]);
  __syncthreads();
  if (t == 0) {
    int best = 0; float bv = dist[0];
    for (int e = 1; e < NEXP; ++e) if (dist[e] < bv) { bv = dist[e]; best = e; }
    eid[b] = best;
  }
}

// ---------------- group samples by expert into tiles of 4 ---------------------
__global__ void group_kernel(const int* __restrict__ eid,
                             int* __restrict__ tile_eid, int* __restrict__ tile_sid) {
  if (threadIdx.x == 0) {
    for (int t = 0; t < MAXT; ++t) tile_eid[t] = -1;
    for (int i = 0; i < MAXT * 4; ++i) tile_sid[i] = -1;
    int nt = 0;
    for (int e = 0; e < NEXP; ++e) {
      int slot = 4;
      for (int b = 0; b < NB; ++b) {
        if (eid[b] == e) {
          if (slot == 4) { tile_eid[nt] = e; nt++; slot = 0; }
          tile_sid[(nt - 1) * 4 + slot] = b;
          slot++;
        }
      }
    }
  }
}

// ---------------- fp32 -> f16 elementwise ------------------------------------
__global__ __launch_bounds__(256) void cvt_f16(const float* __restrict__ in,
                                               _Float16* __restrict__ out, int n4) {
  int i = blockIdx.x * 256 + threadIdx.x;
  if (i < n4) {
    float4 v = ((const float4*)in)[i];
    out[i * 4 + 0] = (_Float16)v.x;
    out[i * 4 + 1] = (_Float16)v.y;
    out[i * 4 + 2] = (_Float16)v.z;
    out[i * 4 + 3] = (_Float16)v.w;
  }
}

// ---------------- weight transpose+convert: [E][K][N] f32 -> [E][N][K] f16 ----
__global__ __launch_bounds__(256) void transpose_cvt(
    const float* __restrict__ in, _Float16* __restrict__ out,
    int K, int N, size_t outEstride) {
  __shared__ float tile[32][33];
  int e = blockIdx.z;
  const float* ip = in + (size_t)e * K * N;
  _Float16* op = out + (size_t)e * outEstride;
  int nb = blockIdx.x * 32, kb = blockIdx.y * 32;
  int tx = threadIdx.x & 31, ty = threadIdx.x >> 5;
  for (int i = ty; i < 32; i += 8)
    tile[i][tx] = ip[(size_t)(kb + i) * N + nb + tx];
  __syncthreads();
  for (int i = ty; i < 32; i += 8)
    op[(size_t)(nb + i) * K + kb + tx] = (_Float16)tile[tx][i];
}

__global__ __launch_bounds__(256) void concat_bias(
    const float* __restrict__ bq, const float* __restrict__ bk,
    const float* __restrict__ bv, float* __restrict__ bqkv) {
  int i = blockIdx.x * 256 + threadIdx.x;
  if (i < NEXP * QKVN) {
    int e = i / QKVN, n = i % QKVN;
    float v = (n < HDIM) ? bq[e * HDIM + n]
            : (n < 2 * HDIM) ? bk[e * HDIM + n - HDIM]
                             : bv[e * HDIM + n - 2 * HDIM];
    bqkv[i] = v;
  }
}

// ---------------- grouped MFMA GEMM: 512x128 tile over 4 same-expert samples --
// A: [64][SEQ][K] f16; Wt: [E][N][K] f16; C: f16 [64][SEQ][N] or f32 partials
// [SPLITK][64][SEQ][N]. 512 threads = 8 waves; wave w: rows [w*64, w*64+64).
template <int OUT_F16, int GELU, int SPLITK>
__global__ __launch_bounds__(512, 2) void gemm_g4(
    const _Float16* __restrict__ A, const _Float16* __restrict__ Wt,
    const float* __restrict__ Ball,
    const int* __restrict__ tile_eid, const int* __restrict__ tile_sid,
    void* __restrict__ Cv, int K, int N) {
  int tile = blockIdx.y;
  int e = tile_eid[tile];
  if (e < 0) return;  // uniform across block
  int sid[4];
#pragma unroll
  for (int i = 0; i < 4; ++i) sid[i] = tile_sid[tile * 4 + i];
  int col0 = blockIdx.x * 128;
  const int Kp = K / SPLITK;
  int kbeg = blockIdx.z * Kp;

  int t = threadIdx.x;
  int w = t >> 6, lane = t & 63, quad = lane >> 4, l16 = lane & 15;

  __shared__ __align__(16) _Float16 As[512 * 32];
  __shared__ __align__(16) _Float16 Bs[128 * 32];

  // staging: elem = t*8 within a 128x32 subtile; issue i = subtile i
  int selem = t * 8;
  int arow = selem >> 5;   // 0..127
  int ak = selem & 31;
  const _Float16* ga[4];
#pragma unroll
  for (int i = 0; i < 4; ++i) {
    int s = (sid[i] < 0) ? sid[0] : sid[i];
    ga[i] = A + (size_t)s * SEQ * K + (size_t)arow * K + kbeg + ak;
  }
  const _Float16* gb = Wt + (size_t)e * N * K + (size_t)(col0 + arow) * K + kbeg + ak;
  _Float16* lA = As + selem;
  _Float16* lB = Bs + selem;

  f32x4 acc[4][8];
#pragma unroll
  for (int i = 0; i < 4; ++i)
#pragma unroll
    for (int j = 0; j < 8; ++j) acc[i][j] = (f32x4){0.f, 0.f, 0.f, 0.f};

  for (int kk = 0; kk < Kp; kk += 32) {
#pragma unroll
    for (int i = 0; i < 4; ++i) gld_lds16(ga[i] + kk, lA + i * 4096);
    gld_lds16(gb + kk, lB);
    __syncthreads();
    f16x8 af[4], bf[8];
#pragma unroll
    for (int i = 0; i < 4; ++i)
      af[i] = *(const f16x8*)&As[(w * 64 + i * 16 + l16) * 32 + quad * 8];
#pragma unroll
    for (int j = 0; j < 8; ++j)
      bf[j] = *(const f16x8*)&Bs[(j * 16 + l16) * 32 + quad * 8];
#pragma unroll
    for (int i = 0; i < 4; ++i)
#pragma unroll
      for (int j = 0; j < 8; ++j)
        acc[i][j] = __builtin_amdgcn_mfma_f32_16x16x32_f16(af[i], bf[j], acc[i][j], 0, 0, 0);
    __syncthreads();
  }

  int sw = sid[w >> 1];          // wave's sample (rows w*64.. all in subtile w>>1)
  if (sw < 0) return;            // wave-uniform, after all barriers
  const float* bias = Ball + (size_t)e * N;

  if (OUT_F16) {
    _Float16* Ch = (_Float16*)Cv + (size_t)sw * SEQ * N;
#pragma unroll
    for (int i = 0; i < 4; ++i)
#pragma unroll
      for (int j = 0; j < 8; ++j) {
        int col = col0 + j * 16 + l16;
        float bv = bias[col];
#pragma unroll
        for (int r = 0; r < 4; ++r) {
          int row = (w & 1) * 64 + i * 16 + quad * 4 + r;
          float v = acc[i][j][r] + bv;
          if (GELU) v = gelu_tanh(v);
          Ch[(size_t)row * N + col] = (_Float16)v;
        }
      }
  } else {
    float* Cf = (float*)Cv + (size_t)blockIdx.z * NB * SEQ * N + (size_t)sw * SEQ * N;
    float bscale = (blockIdx.z == 0) ? 1.f : 0.f;
#pragma unroll
    for (int i = 0; i < 4; ++i)
#pragma unroll
      for (int j = 0; j < 8; ++j) {
        int col = col0 + j * 16 + l16;
        float bv = bias[col] * bscale;
#pragma unroll
        for (int r = 0; r < 4; ++r) {
          int row = (w & 1) * 64 + i * 16 + quad * 4 + r;
          Cf[(size_t)row * N + col] = acc[i][j][r] + bv;
        }
      }
  }
}

// ---------------- MFMA attention: one block per (head, sample) ----------------
__global__ __launch_bounds__(256) void attn_mfma(
    const _Float16* __restrict__ QKV, const float* __restrict__ mask,
    _Float16* __restrict__ Ctx) {
  int h = blockIdx.x, b = blockIdx.y;
  int t = threadIdx.x;
  int w = t >> 6, lane = t & 63, quad = lane >> 4, l16 = lane & 15;

  __shared__ __align__(16) char smem[54784];
  _Float16* Qs = (_Float16*)smem;                 // [128][72]
  _Float16* Ks = (_Float16*)(smem + 18432);       // [128][72]
  _Float16* Ps = (_Float16*)smem;                 // [128][136]
  _Float16* Vt = (_Float16*)(smem + 36864);       // [64][136]
  float* mrow = (float*)(smem + 54272);           // [128]

  const _Float16* Qb = QKV + (size_t)b * SEQ * QKVN + h * HEADD;
  const _Float16* Kb = Qb + HDIM;
  const _Float16* Vb = Qb + 2 * HDIM;

#pragma unroll
  for (int it = 0; it < 4; ++it) {
    int chunk = t + it * 256;
    int row = chunk >> 3, c = chunk & 7;
    *(f16x8*)&Qs[row * 72 + c * 8] = *(const f16x8*)(Qb + (size_t)row * QKVN + c * 8);
    *(f16x8*)&Ks[row * 72 + c * 8] = *(const f16x8*)(Kb + (size_t)row * QKVN + c * 8);
  }
  {
    int vc = t & 7, vjp0 = t >> 3;
#pragma unroll
    for (int it = 0; it < 2; ++it) {
      int jp = vjp0 + it * 32;
      f16x8 v0 = *(const f16x8*)(Vb + (size_t)(2 * jp) * QKVN + vc * 8);
      f16x8 v1 = *(const f16x8*)(Vb + (size_t)(2 * jp + 1) * QKVN + vc * 8);
#pragma unroll
      for (int i = 0; i < 8; ++i) {
        int d = vc * 8 + i;
        unsigned ua = __builtin_bit_cast(unsigned short, (_Float16)v0[i]);
        unsigned ub = __builtin_bit_cast(unsigned short, (_Float16)v1[i]);
        ((unsigned*)Vt)[d * 68 + jp] = ua | (ub << 16);
      }
    }
  }
  if (t < SEQ) mrow[t] = mask[(size_t)b * SEQ + t];
  __syncthreads();

  int m0 = w * 32;
  f32x4 accs[2][8];
#pragma unroll
  for (int i = 0; i < 2; ++i)
#pragma unroll
    for (int j = 0; j < 8; ++j) accs[i][j] = (f32x4){0.f, 0.f, 0.f, 0.f};

#pragma unroll
  for (int ks = 0; ks < 2; ++ks) {
    int k0 = ks * 32 + quad * 8;
    f16x8 af[2], bf[8];
#pragma unroll
    for (int i = 0; i < 2; ++i)
      af[i] = *(const f16x8*)&Qs[(m0 + i * 16 + l16) * 72 + k0];
#pragma unroll
    for (int j = 0; j < 8; ++j)
      bf[j] = *(const f16x8*)&Ks[(j * 16 + l16) * 72 + k0];
#pragma unroll
    for (int i = 0; i < 2; ++i)
#pragma unroll
      for (int j = 0; j < 8; ++j)
        accs[i][j] = __builtin_amdgcn_mfma_f32_16x16x32_f16(af[i], bf[j], accs[i][j], 0, 0, 0);
  }
  __syncthreads();

  float mv[8];
#pragma unroll
  for (int j = 0; j < 8; ++j) mv[j] = mrow[j * 16 + l16];

  float linv[2][4];
#pragma unroll
  for (int i = 0; i < 2; ++i) {
#pragma unroll
    for (int j = 0; j < 8; ++j)
#pragma unroll
      for (int r = 0; r < 4; ++r)
        accs[i][j][r] = accs[i][j][r] * 0.125f + mv[j];
#pragma unroll
    for (int r = 0; r < 4; ++r) {
      float m = accs[i][0][r];
#pragma unroll
      for (int j = 1; j < 8; ++j) m = fmaxf(m, accs[i][j][r]);
      m = fmaxf(m, __shfl_xor(m, 1));
      m = fmaxf(m, __shfl_xor(m, 2));
      m = fmaxf(m, __shfl_xor(m, 4));
      m = fmaxf(m, __shfl_xor(m, 8));
      float sum = 0.f;
#pragma unroll
      for (int j = 0; j < 8; ++j) {
        float p = __expf(accs[i][j][r] - m);
        accs[i][j][r] = p;
        sum += p;
      }
      sum += __shfl_xor(sum, 1);
      sum += __shfl_xor(sum, 2);
      sum += __shfl_xor(sum, 4);
      sum += __shfl_xor(sum, 8);
      linv[i][r] = 1.f / sum;
    }
    int rowb = m0 + i * 16 + quad * 4;
#pragma unroll
    for (int j = 0; j < 8; ++j)
#pragma unroll
      for (int r = 0; r < 4; ++r)
        Ps[(rowb + r) * 136 + j * 16 + l16] = (_Float16)accs[i][j][r];
  }
  __syncthreads();

  f32x4 acco[2][4];
#pragma unroll
  for (int i = 0; i < 2; ++i)
#pragma unroll
    for (int j = 0; j < 4; ++j) acco[i][j] = (f32x4){0.f, 0.f, 0.f, 0.f};

#pragma unroll
  for (int ks = 0; ks < 4; ++ks) {
    int k0 = ks * 32 + quad * 8;
    f16x8 pa[2], vf[4];
#pragma unroll
    for (int i = 0; i < 2; ++i)
      pa[i] = *(const f16x8*)&Ps[(m0 + i * 16 + l16) * 136 + k0];
#pragma unroll
    for (int j = 0; j < 4; ++j)
      vf[j] = *(const f16x8*)&Vt[(j * 16 + l16) * 136 + k0];
#pragma unroll
    for (int i = 0; i < 2; ++i)
#pragma unroll
      for (int j = 0; j < 4; ++j)
        acco[i][j] = __builtin_amdgcn_mfma_f32_16x16x32_f16(pa[i], vf[j], acco[i][j], 0, 0, 0);
  }

  _Float16* Cb = Ctx + (size_t)b * SEQ * HDIM + h * HEADD;
#pragma unroll
  for (int i = 0; i < 2; ++i)
#pragma unroll
    for (int j = 0; j < 4; ++j)
#pragma unroll
      for (int r = 0; r < 4; ++r) {
        int row = m0 + i * 16 + quad * 4 + r;
        int d = j * 16 + l16;
        Cb[(size_t)row * HDIM + d] = (_Float16)(acco[i][j][r] * linv[i][r]);
      }
}

// ---------------- residual + NP partials + layernorm ---------------------------
template <int NP>
__global__ __launch_bounds__(256) void resid_ln_kernel(
    const float* __restrict__ X, const float* __restrict__ P0,
    const float* __restrict__ P1,
    const float* __restrict__ Gall, const float* __restrict__ Ball,
    const int* __restrict__ eid, float* __restrict__ Out,
    _Float16* __restrict__ Out16) {
  int row = blockIdx.x, b = blockIdx.y, t = threadIdx.x;
  int e = eid[b];
  size_t off = ((size_t)b * SEQ + row) * HDIM;
  const float* x = X + off;
  const float* p0 = P0 + off;
  const float* p1 = (NP > 1) ? P1 + off : nullptr;
  float* o = Out + off;
  const float* g = Gall + (size_t)e * HDIM;
  const float* bb = Ball + (size_t)e * HDIM;

  __shared__ float buf[HDIM];
  __shared__ float red[256];

  float s = 0.f;
  for (int h = t; h < HDIM; h += 256) {
    float v = x[h] + p0[h];
    if (NP > 1) v += p1[h];
    buf[h] = v;
    s += v;
  }
  red[t] = s;
  __syncthreads();
  for (int off2 = 128; off2 > 0; off2 >>= 1) {
    if (t < off2) red[t] += red[t + off2];
    __syncthreads();
  }
  float mean = red[0] * (1.0f / HDIM);
  __syncthreads();

  float s2 = 0.f;
  for (int h = t; h < HDIM; h += 256) {
    float d = buf[h] - mean;
    s2 += d * d;
  }
  red[t] = s2;
  __syncthreads();
  for (int off2 = 128; off2 > 0; off2 >>= 1) {
    if (t < off2) red[t] += red[t + off2];
    __syncthreads();
  }
  float var = red[0] * (1.0f / HDIM);
  float rs = rsqrtf(var + 1e-12f);

  for (int h = t; h < HDIM; h += 256) {
    float v = (buf[h] - mean) * rs * g[h] + bb[h];
    o[h] = v;
    if (Out16) Out16[off + h] = (_Float16)v;
  }
}

// ------------------------------------------------------------------------------
extern "C" void kernel_launch(void* const* d_in, const int* in_sizes, int n_in,
                              void* d_out, int out_size, void* d_ws, size_t ws_size,
                              hipStream_t stream) {
  const float* hs   = (const float*)d_in[0];
  const float* mask = (const float*)d_in[1];
  const float* cen  = (const float*)d_in[2];
  const float* wq = (const float*)d_in[3];
  const float* wk = (const float*)d_in[4];
  const float* wv = (const float*)d_in[5];
  const float* wo = (const float*)d_in[6];
  const float* bq = (const float*)d_in[7];
  const float* bk = (const float*)d_in[8];
  const float* bv = (const float*)d_in[9];
  const float* bo = (const float*)d_in[10];
  const float* ln1g = (const float*)d_in[11];
  const float* ln1b = (const float*)d_in[12];
  const float* w1 = (const float*)d_in[13];
  const float* b1 = (const float*)d_in[14];
  const float* w2 = (const float*)d_in[15];
  const float* b2 = (const float*)d_in[16];
  const float* ln2g = (const float*)d_in[17];
  const float* ln2b = (const float*)d_in[18];
  float* out = (float*)d_out;

  const size_t sh = (size_t)SEQ * HDIM;

  char* p = (char*)d_ws;
  int* eid = (int*)p;                 p += 256;
  int* tile_eid = (int*)p;            p += 128;
  int* tile_sid = (int*)p;            p += 512;
  float* bqkv = (float*)p;            p += (size_t)NEXP * QKVN * 4;
  _Float16* Wqkvt = (_Float16*)p;     p += (size_t)NEXP * QKVN * HDIM * 2;
  _Float16* Wot = (_Float16*)p;       p += (size_t)NEXP * HDIM * HDIM * 2;
  _Float16* W1t = (_Float16*)p;       p += (size_t)NEXP * FFDIM * HDIM * 2;
  _Float16* W2t = (_Float16*)p;       p += (size_t)NEXP * HDIM * FFDIM * 2;
  _Float16* x16 = (_Float16*)p;       p += (size_t)NB * sh * 2;

  // activation region (overlaid):
  // region (qkv f16, 37.75 MB) + ctx16 (12.6 MB)  <- later w2 f32 partials (50.33 MB)
  char* region = p;                   p += (size_t)NB * SEQ * QKVN * 2;
  _Float16* ctx16 = (_Float16*)p;     p += (size_t)NB * sh * 2;
  float* aof = (float*)p;             p += (size_t)NB * sh * 4;
  _Float16* ao16 = (_Float16*)p;      p += (size_t)NB * sh * 2;
  char* ffreg = p;                    p += (size_t)NB * SEQ * FFDIM * 2;  // ff16 / wo partials

  float* woparts = (float*)ffreg;     // 2 x [64][128][768] f32 = 50.33 MB
  float* w2parts = (float*)region;    // 2 x [64][128][768] f32 = 50.33 MB
  _Float16* ff16 = (_Float16*)ffreg;

  route_kernel<<<NB, 256, 0, stream>>>(hs, cen, eid);
  group_kernel<<<1, 64, 0, stream>>>(eid, tile_eid, tile_sid);
  cvt_f16<<<(int)((NB * sh / 4 + 255) / 256), 256, 0, stream>>>(hs, x16, (int)(NB * sh / 4));
  concat_bias<<<(NEXP * QKVN + 255) / 256, 256, 0, stream>>>(bq, bk, bv, bqkv);
  transpose_cvt<<<dim3(HDIM / 32, HDIM / 32, NEXP), 256, 0, stream>>>(
      wq, Wqkvt + 0 * HDIM * HDIM, HDIM, HDIM, (size_t)QKVN * HDIM);
  transpose_cvt<<<dim3(HDIM / 32, HDIM / 32, NEXP), 256, 0, stream>>>(
      wk, Wqkvt + 1 * HDIM * HDIM, HDIM, HDIM, (size_t)QKVN * HDIM);
  transpose_cvt<<<dim3(HDIM / 32, HDIM / 32, NEXP), 256, 0, stream>>>(
      wv, Wqkvt + 2 * HDIM * HDIM, HDIM, HDIM, (size_t)QKVN * HDIM);
  transpose_cvt<<<dim3(HDIM / 32, HDIM / 32, NEXP), 256, 0, stream>>>(
      wo, Wot, HDIM, HDIM, (size_t)HDIM * HDIM);
  transpose_cvt<<<dim3(FFDIM / 32, HDIM / 32, NEXP), 256, 0, stream>>>(
      w1, W1t, HDIM, FFDIM, (size_t)FFDIM * HDIM);
  transpose_cvt<<<dim3(HDIM / 32, FFDIM / 32, NEXP), 256, 0, stream>>>(
      w2, W2t, FFDIM, HDIM, (size_t)HDIM * FFDIM);

  // QKV fused: f16 out -> region
  gemm_g4<1, 0, 1><<<dim3(QKVN / 128, MAXT, 1), 512, 0, stream>>>(
      x16, Wqkvt, bqkv, tile_eid, tile_sid, region, HDIM, QKVN);
  // attention -> ctx16
  attn_mfma<<<dim3(NHEAD, NB), 256, 0, stream>>>(
      (const _Float16*)region, mask, ctx16);
  // wo, split-K=2 -> woparts (in ff region)
  gemm_g4<0, 0, 2><<<dim3(HDIM / 128, MAXT, 2), 512, 0, stream>>>(
      ctx16, Wot, bo, tile_eid, tile_sid, woparts, HDIM, HDIM);
  // LN1 = LN(hs + p0 + p1) -> aof + ao16
  resid_ln_kernel<2><<<dim3(SEQ, NB), 256, 0, stream>>>(
      hs, woparts, woparts + (size_t)NB * sh, ln1g, ln1b, eid, aof, ao16);
  // w1 + GELU: f16 -> ff16 (overwrites woparts)
  gemm_g4<1, 1, 1><<<dim3(FFDIM / 128, MAXT, 1), 512, 0, stream>>>(
      ao16, W1t, b1, tile_eid, tile_sid, ff16, HDIM, FFDIM);
  // w2, split-K=2 -> w2parts (in qkv region)
  gemm_g4<0, 0, 2><<<dim3(HDIM / 128, MAXT, 2), 512, 0, stream>>>(
      ff16, W2t, b2, tile_eid, tile_sid, w2parts, FFDIM, HDIM);
  // LN2 = LN(aof + p0 + p1) -> out
  resid_ln_kernel<2><<<dim3(SEQ, NB), 256, 0, stream>>>(
      aof, w2parts, w2parts + (size_t)NB * sh, ln2g, ln2b, eid, out,
      (_Float16*)nullptr);
}

// Round 5
// 541.655 us; speedup vs baseline: 1.1601x; 1.1601x over previous
//
#include <hip/hip_runtime.h>
#include <hip/hip_bf16.h>
#include <math.h>

#define HDIM 768
#define NHEAD 12
#define HEADD 64
#define FFDIM 3072
#define NEXP 4
#define SEQ 128
#define NB 64
#define QKVN 2304

typedef __attribute__((ext_vector_type(8))) _Float16 f16x8;
typedef __attribute__((ext_vector_type(4))) float f32x4;

__device__ __forceinline__ float gelu_tanh(float x) {
  float x3 = x * x * x;
  return 0.5f * x * (1.0f + tanhf(0.7978845608028654f * (x + 0.044715f * x3)));
}

__device__ __forceinline__ void gld_lds16(const void* g, void* l) {
  __builtin_amdgcn_global_load_lds(
      (const __attribute__((address_space(1))) unsigned int*)g,
      (__attribute__((address_space(3))) unsigned int*)l, 16, 0, 0);
}

// ---------------- routing ----------------------------------------------------
__global__ __launch_bounds__(256) void route_kernel(
    const float* __restrict__ hs, const float* __restrict__ centers,
    int* __restrict__ eid) {
  int b = blockIdx.x, t = threadIdx.x;
  __shared__ float hp[HDIM];
  __shared__ float dist[NEXP];
  const float* xb = hs + (size_t)b * SEQ * HDIM;
  for (int h = t; h < HDIM; h += 256) {
    float s = 0.f;
    for (int sq = 0; sq < SEQ; ++sq) s += xb[(size_t)sq * HDIM + h];
    hp[h] = s * (1.0f / SEQ);
  }
  if (t < NEXP) dist[t] = 0.f;
  __syncthreads();
  float pe[NEXP] = {0.f, 0.f, 0.f, 0.f};
  for (int h = t; h < HDIM; h += 256) {
    float v = hp[h];
#pragma unroll
    for (int e = 0; e < NEXP; ++e) {
      float d = v - centers[e * HDIM + h];
      pe[e] += d * d;
    }
  }
#pragma unroll
  for (int e = 0; e < NEXP; ++e) atomicAdd(&dist[e], pe[e]);
  __syncthreads();
  if (t == 0) {
    int best = 0; float bv = dist[0];
    for (int e = 1; e < NEXP; ++e) if (dist[e] < bv) { bv = dist[e]; best = e; }
    eid[b] = best;
  }
}

// ---------------- sort samples by expert --------------------------------------
__global__ void sort_kernel(const int* __restrict__ eid,
                            int* __restrict__ order, int* __restrict__ ord_eid) {
  if (threadIdx.x == 0) {
    int n = 0;
    for (int e = 0; e < NEXP; ++e)
      for (int b = 0; b < NB; ++b)
        if (eid[b] == e) { order[n] = b; ord_eid[n] = e; n++; }
  }
}

// ---------------- fp32 -> f16 elementwise ------------------------------------
__global__ __launch_bounds__(256) void cvt_f16(const float* __restrict__ in,
                                               _Float16* __restrict__ out, int n4) {
  int i = blockIdx.x * 256 + threadIdx.x;
  if (i < n4) {
    float4 v = ((const float4*)in)[i];
    out[i * 4 + 0] = (_Float16)v.x;
    out[i * 4 + 1] = (_Float16)v.y;
    out[i * 4 + 2] = (_Float16)v.z;
    out[i * 4 + 3] = (_Float16)v.w;
  }
}

// ---------------- weight transpose+convert: [E][K][N] f32 -> [E][N][K] f16 ----
__global__ __launch_bounds__(256) void transpose_cvt(
    const float* __restrict__ in, _Float16* __restrict__ out,
    int K, int N, size_t outEstride) {
  __shared__ float tile[32][33];
  int e = blockIdx.z;
  const float* ip = in + (size_t)e * K * N;
  _Float16* op = out + (size_t)e * outEstride;
  int nb = blockIdx.x * 32, kb = blockIdx.y * 32;
  int tx = threadIdx.x & 31, ty = threadIdx.x >> 5;
  for (int i = ty; i < 32; i += 8)
    tile[i][tx] = ip[(size_t)(kb + i) * N + nb + tx];
  __syncthreads();
  for (int i = ty; i < 32; i += 8)
    op[(size_t)(nb + i) * K + kb + tx] = (_Float16)tile[tx][i];
}

__global__ __launch_bounds__(256) void concat_bias(
    const float* __restrict__ bq, const float* __restrict__ bk,
    const float* __restrict__ bv, float* __restrict__ bqkv) {
  int i = blockIdx.x * 256 + threadIdx.x;
  if (i < NEXP * QKVN) {
    int e = i / QKVN, n = i % QKVN;
    float v = (n < HDIM) ? bq[e * HDIM + n]
            : (n < 2 * HDIM) ? bk[e * HDIM + n - HDIM]
                             : bv[e * HDIM + n - 2 * HDIM];
    bqkv[i] = v;
  }
}

// ---------------- MFMA GEMM with XCD-pinned swizzle + optional split-K --------
// Grid: dim3(GX*64, SPLITK). Linear id L -> (x, z) with all x of sample-slot z
// on XCD z&7 (L = GX*8*(z>>3) + 8x + (z&7)). z indexes expert-sorted order.
// A: [64][SEQ][K] f16; Wt: [E][N][K]; C: f16 [64][SEQ][N] or f32 partials
// [SPLITK][64][SEQ][N] (bias folded into partial 0).
template <int OUT_F16, int GELU, int SPLITK>
__global__ __launch_bounds__(256) void gemm_mfma(
    const _Float16* __restrict__ A, const _Float16* __restrict__ Wt,
    const float* __restrict__ Ball, const int* __restrict__ order,
    const int* __restrict__ ord_eid, void* __restrict__ Cv, int K, int N) {
  int GX = N >> 7;
  int L = blockIdx.x;
  int low3 = L & 7, Mq = L >> 3;
  int x = Mq % GX, zhi = Mq / GX;
  int z = zhi * 8 + low3;
  int b = order[z];
  int e = ord_eid[z];
  int col0 = x * 128;
  int kz = blockIdx.y;
  const int Kp = K / SPLITK;
  int kbeg = kz * Kp;

  int t = threadIdx.x;
  int lane = t & 63, w = t >> 6;
  int quad = lane >> 4, l16 = lane & 15;
  int wr = (w >> 1) * 64, wc = (w & 1) * 64;

  __shared__ __align__(16) _Float16 As[128 * 32];
  __shared__ __align__(16) _Float16 Bs[128 * 32];

  const _Float16* Ab = A + (size_t)b * SEQ * K + kbeg;
  const _Float16* Wb = Wt + (size_t)e * N * K + (size_t)col0 * K + kbeg;

  int e0 = t * 8, e1 = 2048 + t * 8;
  int m0 = e0 >> 5, k0e = e0 & 31;
  int m1 = e1 >> 5, k1e = e1 & 31;
  const _Float16* ga0 = Ab + (size_t)m0 * K + k0e;
  const _Float16* ga1 = Ab + (size_t)m1 * K + k1e;
  const _Float16* gb0 = Wb + (size_t)m0 * K + k0e;
  const _Float16* gb1 = Wb + (size_t)m1 * K + k1e;
  _Float16* lA0 = &As[e0]; _Float16* lA1 = &As[e1];
  _Float16* lB0 = &Bs[e0]; _Float16* lB1 = &Bs[e1];

  f32x4 acc[4][4];
#pragma unroll
  for (int i = 0; i < 4; ++i)
#pragma unroll
    for (int j = 0; j < 4; ++j) acc[i][j] = (f32x4){0.f, 0.f, 0.f, 0.f};

  for (int kk = 0; kk < Kp; kk += 32) {
    gld_lds16(ga0 + kk, lA0);
    gld_lds16(ga1 + kk, lA1);
    gld_lds16(gb0 + kk, lB0);
    gld_lds16(gb1 + kk, lB1);
    __syncthreads();
    f16x8 af[4], bf[4];
#pragma unroll
    for (int i = 0; i < 4; ++i)
      af[i] = *(const f16x8*)&As[(wr + i * 16 + l16) * 32 + quad * 8];
#pragma unroll
    for (int i = 0; i < 4; ++i)
      bf[i] = *(const f16x8*)&Bs[(wc + i * 16 + l16) * 32 + quad * 8];
#pragma unroll
    for (int i = 0; i < 4; ++i)
#pragma unroll
      for (int j = 0; j < 4; ++j)
        acc[i][j] = __builtin_amdgcn_mfma_f32_16x16x32_f16(af[i], bf[j], acc[i][j], 0, 0, 0);
    __syncthreads();
  }

  const float* bias = Ball + (size_t)e * N;

  if (OUT_F16) {
    _Float16* Ch = (_Float16*)Cv + (size_t)b * SEQ * N;
#pragma unroll
    for (int i = 0; i < 4; ++i)
#pragma unroll
      for (int j = 0; j < 4; ++j) {
        int col = col0 + wc + j * 16 + l16;
        float bv = bias[col];
#pragma unroll
        for (int r = 0; r < 4; ++r) {
          int row = wr + i * 16 + quad * 4 + r;
          float v = acc[i][j][r] + bv;
          if (GELU) v = gelu_tanh(v);
          Ch[(size_t)row * N + col] = (_Float16)v;
        }
      }
  } else {
    float* Cf = (float*)Cv + (size_t)kz * NB * SEQ * N + (size_t)b * SEQ * N;
    float bscale = (kz == 0) ? 1.f : 0.f;
#pragma unroll
    for (int i = 0; i < 4; ++i)
#pragma unroll
      for (int j = 0; j < 4; ++j) {
        int col = col0 + wc + j * 16 + l16;
        float bv = bias[col] * bscale;
#pragma unroll
        for (int r = 0; r < 4; ++r) {
          int row = wr + i * 16 + quad * 4 + r;
          Cf[(size_t)row * N + col] = acc[i][j][r] + bv;
        }
      }
  }
}

// ---------------- MFMA attention: one block per (head, sample) ----------------
__global__ __launch_bounds__(256) void attn_mfma(
    const _Float16* __restrict__ QKV, const float* __restrict__ mask,
    _Float16* __restrict__ Ctx) {
  int h = blockIdx.x, b = blockIdx.y;
  int t = threadIdx.x;
  int w = t >> 6, lane = t & 63, quad = lane >> 4, l16 = lane & 15;

  __shared__ __align__(16) char smem[54784];
  _Float16* Qs = (_Float16*)smem;                 // [128][72]
  _Float16* Ks = (_Float16*)(smem + 18432);       // [128][72]
  _Float16* Ps = (_Float16*)smem;                 // [128][136]
  _Float16* Vt = (_Float16*)(smem + 36864);       // [64][136]
  float* mrow = (float*)(smem + 54272);           // [128]

  const _Float16* Qb = QKV + (size_t)b * SEQ * QKVN + h * HEADD;
  const _Float16* Kb = Qb + HDIM;
  const _Float16* Vb = Qb + 2 * HDIM;

#pragma unroll
  for (int it = 0; it < 4; ++it) {
    int chunk = t + it * 256;
    int row = chunk >> 3, c = chunk & 7;
    *(f16x8*)&Qs[row * 72 + c * 8] = *(const f16x8*)(Qb + (size_t)row * QKVN + c * 8);
    *(f16x8*)&Ks[row * 72 + c * 8] = *(const f16x8*)(Kb + (size_t)row * QKVN + c * 8);
  }
  {
    int vc = t & 7, vjp0 = t >> 3;
#pragma unroll
    for (int it = 0; it < 2; ++it) {
      int jp = vjp0 + it * 32;
      f16x8 v0 = *(const f16x8*)(Vb + (size_t)(2 * jp) * QKVN + vc * 8);
      f16x8 v1 = *(const f16x8*)(Vb + (size_t)(2 * jp + 1) * QKVN + vc * 8);
#pragma unroll
      for (int i = 0; i < 8; ++i) {
        int d = vc * 8 + i;
        unsigned ua = __builtin_bit_cast(unsigned short, (_Float16)v0[i]);
        unsigned ub = __builtin_bit_cast(unsigned short, (_Float16)v1[i]);
        ((unsigned*)Vt)[d * 68 + jp] = ua | (ub << 16);
      }
    }
  }
  if (t < SEQ) mrow[t] = mask[(size_t)b * SEQ + t];
  __syncthreads();

  int m0 = w * 32;
  f32x4 accs[2][8];
#pragma unroll
  for (int i = 0; i < 2; ++i)
#pragma unroll
    for (int j = 0; j < 8; ++j) accs[i][j] = (f32x4){0.f, 0.f, 0.f, 0.f};

#pragma unroll
  for (int ks = 0; ks < 2; ++ks) {
    int k0 = ks * 32 + quad * 8;
    f16x8 af[2], bf[8];
#pragma unroll
    for (int i = 0; i < 2; ++i)
      af[i] = *(const f16x8*)&Qs[(m0 + i * 16 + l16) * 72 + k0];
#pragma unroll
    for (int j = 0; j < 8; ++j)
      bf[j] = *(const f16x8*)&Ks[(j * 16 + l16) * 72 + k0];
#pragma unroll
    for (int i = 0; i < 2; ++i)
#pragma unroll
      for (int j = 0; j < 8; ++j)
        accs[i][j] = __builtin_amdgcn_mfma_f32_16x16x32_f16(af[i], bf[j], accs[i][j], 0, 0, 0);
  }
  __syncthreads();

  float mv[8];
#pragma unroll
  for (int j = 0; j < 8; ++j) mv[j] = mrow[j * 16 + l16];

  float linv[2][4];
#pragma unroll
  for (int i = 0; i < 2; ++i) {
#pragma unroll
    for (int j = 0; j < 8; ++j)
#pragma unroll
      for (int r = 0; r < 4; ++r)
        accs[i][j][r] = accs[i][j][r] * 0.125f + mv[j];
#pragma unroll
    for (int r = 0; r < 4; ++r) {
      float m = accs[i][0][r];
#pragma unroll
      for (int j = 1; j < 8; ++j) m = fmaxf(m, accs[i][j][r]);
      m = fmaxf(m, __shfl_xor(m, 1));
      m = fmaxf(m, __shfl_xor(m, 2));
      m = fmaxf(m, __shfl_xor(m, 4));
      m = fmaxf(m, __shfl_xor(m, 8));
      float sum = 0.f;
#pragma unroll
      for (int j = 0; j < 8; ++j) {
        float p = __expf(accs[i][j][r] - m);
        accs[i][j][r] = p;
        sum += p;
      }
      sum += __shfl_xor(sum, 1);
      sum += __shfl_xor(sum, 2);
      sum += __shfl_xor(sum, 4);
      sum += __shfl_xor(sum, 8);
      linv[i][r] = 1.f / sum;
    }
    int rowb = m0 + i * 16 + quad * 4;
#pragma unroll
    for (int j = 0; j < 8; ++j)
#pragma unroll
      for (int r = 0; r < 4; ++r)
        Ps[(rowb + r) * 136 + j * 16 + l16] = (_Float16)accs[i][j][r];
  }
  __syncthreads();

  f32x4 acco[2][4];
#pragma unroll
  for (int i = 0; i < 2; ++i)
#pragma unroll
    for (int j = 0; j < 4; ++j) acco[i][j] = (f32x4){0.f, 0.f, 0.f, 0.f};

#pragma unroll
  for (int ks = 0; ks < 4; ++ks) {
    int k0 = ks * 32 + quad * 8;
    f16x8 pa[2], vf[4];
#pragma unroll
    for (int i = 0; i < 2; ++i)
      pa[i] = *(const f16x8*)&Ps[(m0 + i * 16 + l16) * 136 + k0];
#pragma unroll
    for (int j = 0; j < 4; ++j)
      vf[j] = *(const f16x8*)&Vt[(j * 16 + l16) * 136 + k0];
#pragma unroll
    for (int i = 0; i < 2; ++i)
#pragma unroll
      for (int j = 0; j < 4; ++j)
        acco[i][j] = __builtin_amdgcn_mfma_f32_16x16x32_f16(pa[i], vf[j], acco[i][j], 0, 0, 0);
  }

  _Float16* Cb = Ctx + (size_t)b * SEQ * HDIM + h * HEADD;
#pragma unroll
  for (int i = 0; i < 2; ++i)
#pragma unroll
    for (int j = 0; j < 4; ++j)
#pragma unroll
      for (int r = 0; r < 4; ++r) {
        int row = m0 + i * 16 + quad * 4 + r;
        int d = j * 16 + l16;
        Cb[(size_t)row * HDIM + d] = (_Float16)(acco[i][j][r] * linv[i][r]);
      }
}

// ---------------- residual + NP partials + layernorm ---------------------------
template <int NP>
__global__ __launch_bounds__(256) void resid_ln_kernel(
    const float* __restrict__ X, const float* __restrict__ P0,
    const float* __restrict__ P1,
    const float* __restrict__ Gall, const float* __restrict__ Ball,
    const int* __restrict__ eid, float* __restrict__ Out,
    _Float16* __restrict__ Out16) {
  int row = blockIdx.x, b = blockIdx.y, t = threadIdx.x;
  int e = eid[b];
  size_t off = ((size_t)b * SEQ + row) * HDIM;
  const float* x = X + off;
  const float* p0 = P0 + off;
  const float* p1 = (NP > 1) ? P1 + off : nullptr;
  float* o = Out + off;
  const float* g = Gall + (size_t)e * HDIM;
  const float* bb = Ball + (size_t)e * HDIM;

  __shared__ float buf[HDIM];
  __shared__ float red[256];

  float s = 0.f;
  for (int h = t; h < HDIM; h += 256) {
    float v = x[h] + p0[h];
    if (NP > 1) v += p1[h];
    buf[h] = v;
    s += v;
  }
  red[t] = s;
  __syncthreads();
  for (int off2 = 128; off2 > 0; off2 >>= 1) {
    if (t < off2) red[t] += red[t + off2];
    __syncthreads();
  }
  float mean = red[0] * (1.0f / HDIM);
  __syncthreads();

  float s2 = 0.f;
  for (int h = t; h < HDIM; h += 256) {
    float d = buf[h] - mean;
    s2 += d * d;
  }
  red[t] = s2;
  __syncthreads();
  for (int off2 = 128; off2 > 0; off2 >>= 1) {
    if (t < off2) red[t] += red[t + off2];
    __syncthreads();
  }
  float var = red[0] * (1.0f / HDIM);
  float rs = rsqrtf(var + 1e-12f);

  for (int h = t; h < HDIM; h += 256) {
    float v = (buf[h] - mean) * rs * g[h] + bb[h];
    o[h] = v;
    if (Out16) Out16[off + h] = (_Float16)v;
  }
}

// ------------------------------------------------------------------------------
extern "C" void kernel_launch(void* const* d_in, const int* in_sizes, int n_in,
                              void* d_out, int out_size, void* d_ws, size_t ws_size,
                              hipStream_t stream) {
  const float* hs   = (const float*)d_in[0];
  const float* mask = (const float*)d_in[1];
  const float* cen  = (const float*)d_in[2];
  const float* wq = (const float*)d_in[3];
  const float* wk = (const float*)d_in[4];
  const float* wv = (const float*)d_in[5];
  const float* wo = (const float*)d_in[6];
  const float* bq = (const float*)d_in[7];
  const float* bk = (const float*)d_in[8];
  const float* bv = (const float*)d_in[9];
  const float* bo = (const float*)d_in[10];
  const float* ln1g = (const float*)d_in[11];
  const float* ln1b = (const float*)d_in[12];
  const float* w1 = (const float*)d_in[13];
  const float* b1 = (const float*)d_in[14];
  const float* w2 = (const float*)d_in[15];
  const float* b2 = (const float*)d_in[16];
  const float* ln2g = (const float*)d_in[17];
  const float* ln2b = (const float*)d_in[18];
  float* out = (float*)d_out;

  const size_t sh = (size_t)SEQ * HDIM;

  char* p = (char*)d_ws;
  int* eid = (int*)p;                 p += 256;
  int* order = (int*)p;               p += 256;
  int* ord_eid = (int*)p;             p += 256;
  float* bqkv = (float*)p;            p += (size_t)NEXP * QKVN * 4;
  _Float16* Wqkvt = (_Float16*)p;     p += (size_t)NEXP * QKVN * HDIM * 2;
  _Float16* Wot = (_Float16*)p;       p += (size_t)NEXP * HDIM * HDIM * 2;
  _Float16* W1t = (_Float16*)p;       p += (size_t)NEXP * FFDIM * HDIM * 2;
  _Float16* W2t = (_Float16*)p;       p += (size_t)NEXP * HDIM * FFDIM * 2;
  _Float16* x16 = (_Float16*)p;       p += (size_t)NB * sh * 2;

  // activation overlays:
  // region (qkv f16 37.75 MB) + ctx16 (12.6 MB)  -> later w2 f32 partials (50.33 MB)
  // ffreg (ff16 50.33 MB) <-> wo f32 partials (50.33 MB)
  char* region = p;                   p += (size_t)NB * SEQ * QKVN * 2;
  _Float16* ctx16 = (_Float16*)p;     p += (size_t)NB * sh * 2;
  float* aof = (float*)p;             p += (size_t)NB * sh * 4;
  _Float16* ao16 = (_Float16*)p;      p += (size_t)NB * sh * 2;
  char* ffreg = p;                    p += (size_t)NB * SEQ * FFDIM * 2;

  float* woparts = (float*)ffreg;
  float* w2parts = (float*)region;
  _Float16* ff16 = (_Float16*)ffreg;

  route_kernel<<<NB, 256, 0, stream>>>(hs, cen, eid);
  sort_kernel<<<1, 64, 0, stream>>>(eid, order, ord_eid);
  cvt_f16<<<(int)((NB * sh / 4 + 255) / 256), 256, 0, stream>>>(hs, x16, (int)(NB * sh / 4));
  concat_bias<<<(NEXP * QKVN + 255) / 256, 256, 0, stream>>>(bq, bk, bv, bqkv);
  transpose_cvt<<<dim3(HDIM / 32, HDIM / 32, NEXP), 256, 0, stream>>>(
      wq, Wqkvt + 0 * HDIM * HDIM, HDIM, HDIM, (size_t)QKVN * HDIM);
  transpose_cvt<<<dim3(HDIM / 32, HDIM / 32, NEXP), 256, 0, stream>>>(
      wk, Wqkvt + 1 * HDIM * HDIM, HDIM, HDIM, (size_t)QKVN * HDIM);
  transpose_cvt<<<dim3(HDIM / 32, HDIM / 32, NEXP), 256, 0, stream>>>(
      wv, Wqkvt + 2 * HDIM * HDIM, HDIM, HDIM, (size_t)QKVN * HDIM);
  transpose_cvt<<<dim3(HDIM / 32, HDIM / 32, NEXP), 256, 0, stream>>>(
      wo, Wot, HDIM, HDIM, (size_t)HDIM * HDIM);
  transpose_cvt<<<dim3(FFDIM / 32, HDIM / 32, NEXP), 256, 0, stream>>>(
      w1, W1t, HDIM, FFDIM, (size_t)FFDIM * HDIM);
  transpose_cvt<<<dim3(HDIM / 32, FFDIM / 32, NEXP), 256, 0, stream>>>(
      w2, W2t, FFDIM, HDIM, (size_t)HDIM * FFDIM);

  // QKV fused -> region (f16)
  gemm_mfma<1, 0, 1><<<dim3((QKVN / 128) * NB, 1), 256, 0, stream>>>(
      x16, Wqkvt, bqkv, order, ord_eid, region, HDIM, QKVN);
  // attention -> ctx16
  attn_mfma<<<dim3(NHEAD, NB), 256, 0, stream>>>(
      (const _Float16*)region, mask, ctx16);
  // wo split-K=2 -> woparts (ffreg)
  gemm_mfma<0, 0, 2><<<dim3((HDIM / 128) * NB, 2), 256, 0, stream>>>(
      ctx16, Wot, bo, order, ord_eid, woparts, HDIM, HDIM);
  // LN1 = LN(hs + p0 + p1) -> aof + ao16
  resid_ln_kernel<2><<<dim3(SEQ, NB), 256, 0, stream>>>(
      hs, woparts, woparts + (size_t)NB * sh, ln1g, ln1b, eid, aof, ao16);
  // w1 + GELU -> ff16 (overwrites woparts, already consumed)
  gemm_mfma<1, 1, 1><<<dim3((FFDIM / 128) * NB, 1), 256, 0, stream>>>(
      ao16, W1t, b1, order, ord_eid, ff16, HDIM, FFDIM);
  // w2 split-K=2 -> w2parts (region; qkv+ctx dead)
  gemm_mfma<0, 0, 2><<<dim3((HDIM / 128) * NB, 2), 256, 0, stream>>>(
      ff16, W2t, b2, order, ord_eid, w2parts, FFDIM, HDIM);
  // LN2 -> out
  resid_ln_kernel<2><<<dim3(SEQ, NB), 256, 0, stream>>>(
      aof, w2parts, w2parts + (size_t)NB * sh, ln2g, ln2b, eid, out,
      (_Float16*)nullptr);
}

// Round 6
// 482.673 us; speedup vs baseline: 1.3018x; 1.1222x over previous
//
#include <hip/hip_runtime.h>
#include <hip/hip_bf16.h>
#include <math.h>

#define HDIM 768
#define NHEAD 12
#define HEADD 64
#define FFDIM 3072
#define NEXP 4
#define SEQ 128
#define NB 64
#define QKVN 2304

typedef __attribute__((ext_vector_type(8))) _Float16 f16x8;
typedef __attribute__((ext_vector_type(4))) _Float16 f16x4;
typedef __attribute__((ext_vector_type(4))) float f32x4;

// gelu_tanh(x) = x * sigmoid(2*0.79788456*(x + 0.044715 x^3)) — exact rewrite,
// ~10 VALU ops vs libm tanhf's ~25+ (w1 epilogue was VALU-bound, r5 VALUBusy=58%)
__device__ __forceinline__ float gelu_fast(float x) {
  float t = -1.5957691216057308f * x * __builtin_fmaf(0.044715f * x, x, 1.0f);
  return x * __builtin_amdgcn_rcpf(1.0f + __expf(t));
}

__device__ __forceinline__ void gld_lds16(const void* g, void* l) {
  __builtin_amdgcn_global_load_lds(
      (const __attribute__((address_space(1))) unsigned int*)g,
      (__attribute__((address_space(3))) unsigned int*)l, 16, 0, 0);
}

// ---------------- routing + fp32->f16 conversion (fused) ----------------------
// One block per sample: stream hs row-major (coalesced float4), emit x16,
// accumulate per-column sums for the routing mean, then argmin distance.
__global__ __launch_bounds__(256) void route_cvt_kernel(
    const float* __restrict__ hs, const float* __restrict__ centers,
    int* __restrict__ eid, _Float16* __restrict__ x16) {
  int b = blockIdx.x, t = threadIdx.x;
  __shared__ float hp[HDIM];
  __shared__ float dist[NEXP];
  const float* xb = hs + (size_t)b * SEQ * HDIM;
  _Float16* ob = x16 + (size_t)b * SEQ * HDIM;

  if (t < 192) {  // 192 float4 per row
    float p0 = 0.f, p1 = 0.f, p2 = 0.f, p3 = 0.f;
    for (int sq = 0; sq < SEQ; ++sq) {
      float4 v = ((const float4*)(xb + (size_t)sq * HDIM))[t];
      p0 += v.x; p1 += v.y; p2 += v.z; p3 += v.w;
      f16x4 h = {(_Float16)v.x, (_Float16)v.y, (_Float16)v.z, (_Float16)v.w};
      *(f16x4*)(ob + (size_t)sq * HDIM + t * 4) = h;
    }
    hp[t * 4 + 0] = p0 * (1.0f / SEQ);
    hp[t * 4 + 1] = p1 * (1.0f / SEQ);
    hp[t * 4 + 2] = p2 * (1.0f / SEQ);
    hp[t * 4 + 3] = p3 * (1.0f / SEQ);
  }
  if (t < NEXP) dist[t] = 0.f;
  __syncthreads();

  float pe[NEXP] = {0.f, 0.f, 0.f, 0.f};
  for (int h = t; h < HDIM; h += 256) {
    float v = hp[h];
#pragma unroll
    for (int e = 0; e < NEXP; ++e) {
      float d = v - centers[e * HDIM + h];
      pe[e] += d * d;
    }
  }
#pragma unroll
  for (int e = 0; e < NEXP; ++e) atomicAdd(&dist[e], pe[e]);
  __syncthreads();
  if (t == 0) {
    int best = 0; float bv = dist[0];
    for (int e = 1; e < NEXP; ++e) if (dist[e] < bv) { bv = dist[e]; best = e; }
    eid[b] = best;
  }
}

// ---------------- ALL weight prep in one launch -------------------------------
// grid (6949, NEXP): x<2304 -> wq/wk/wv/wo 32x32 transpose tiles; [2304,4608)
// w1; [4608,6912) w2; [6912,6948) bias concat (z==0); x==6948 expert sort (z==0).
__device__ __forceinline__ void tr_tile(const float* __restrict__ ip,
                                        _Float16* __restrict__ op,
                                        int K, int N, int nb, int kb,
                                        float (*tile)[33], int t) {
  int tx = t & 31, ty = t >> 5;
  for (int i = ty; i < 32; i += 8)
    tile[i][tx] = ip[(size_t)(kb + i) * N + nb + tx];
  __syncthreads();
  for (int i = ty; i < 32; i += 8)
    op[(size_t)(nb + i) * K + kb + tx] = (_Float16)tile[tx][i];
}

__global__ __launch_bounds__(256) void prep_weights(
    const float* __restrict__ wq, const float* __restrict__ wk,
    const float* __restrict__ wv, const float* __restrict__ wo,
    const float* __restrict__ w1, const float* __restrict__ w2,
    const float* __restrict__ bq, const float* __restrict__ bk,
    const float* __restrict__ bv,
    _Float16* __restrict__ Wqkvt, _Float16* __restrict__ Wot,
    _Float16* __restrict__ W1t, _Float16* __restrict__ W2t,
    float* __restrict__ bqkv, const int* __restrict__ eid,
    int* __restrict__ order, int* __restrict__ ord_eid) {
  __shared__ float tile[32][33];
  int x = blockIdx.x, e = blockIdx.y, t = threadIdx.x;

  if (x < 1728) {  // wq/wk/wv -> Wqkvt [E][2304][768]
    int which = x / 576, local = x % 576;
    const float* src = (which == 0) ? wq : (which == 1) ? wk : wv;
    tr_tile(src + (size_t)e * HDIM * HDIM,
            Wqkvt + (size_t)which * HDIM * HDIM + (size_t)e * QKVN * HDIM,
            HDIM, HDIM, (local % 24) * 32, (local / 24) * 32, tile, t);
  } else if (x < 2304) {  // wo -> Wot [E][768][768]
    int local = x - 1728;
    tr_tile(wo + (size_t)e * HDIM * HDIM, Wot + (size_t)e * HDIM * HDIM,
            HDIM, HDIM, (local % 24) * 32, (local / 24) * 32, tile, t);
  } else if (x < 4608) {  // w1 [768][3072] -> W1t [E][3072][768]
    int local = x - 2304;
    tr_tile(w1 + (size_t)e * HDIM * FFDIM, W1t + (size_t)e * FFDIM * HDIM,
            HDIM, FFDIM, (local % 96) * 32, (local / 96) * 32, tile, t);
  } else if (x < 6912) {  // w2 [3072][768] -> W2t [E][768][3072]
    int local = x - 4608;
    tr_tile(w2 + (size_t)e * FFDIM * HDIM, W2t + (size_t)e * HDIM * FFDIM,
            FFDIM, HDIM, (local % 24) * 32, (local / 24) * 32, tile, t);
  } else if (x < 6948) {  // bias concat (z==0 only)
    if (e == 0) {
      int i = (x - 6912) * 256 + t;
      if (i < NEXP * QKVN) {
        int ee = i / QKVN, n = i % QKVN;
        float v = (n < HDIM) ? bq[ee * HDIM + n]
                : (n < 2 * HDIM) ? bk[ee * HDIM + n - HDIM]
                                 : bv[ee * HDIM + n - 2 * HDIM];
        bqkv[i] = v;
      }
    }
  } else {  // expert sort (z==0, single thread)
    if (e == 0 && t == 0) {
      int n = 0;
      for (int ee = 0; ee < NEXP; ++ee)
        for (int b = 0; b < NB; ++b)
          if (eid[b] == ee) { order[n] = b; ord_eid[n] = ee; n++; }
    }
  }
}

// ---------------- MFMA GEMM with XCD-pinned swizzle + optional split-K --------
template <int OUT_F16, int GELU, int SPLITK>
__global__ __launch_bounds__(256) void gemm_mfma(
    const _Float16* __restrict__ A, const _Float16* __restrict__ Wt,
    const float* __restrict__ Ball, const int* __restrict__ order,
    const int* __restrict__ ord_eid, void* __restrict__ Cv, int K, int N) {
  int GX = N >> 7;
  int L = blockIdx.x;
  int low3 = L & 7, Mq = L >> 3;
  int x = Mq % GX, zhi = Mq / GX;
  int z = zhi * 8 + low3;
  int b = order[z];
  int e = ord_eid[z];
  int col0 = x * 128;
  int kz = blockIdx.y;
  const int Kp = K / SPLITK;
  int kbeg = kz * Kp;

  int t = threadIdx.x;
  int lane = t & 63, w = t >> 6;
  int quad = lane >> 4, l16 = lane & 15;
  int wr = (w >> 1) * 64, wc = (w & 1) * 64;

  __shared__ __align__(16) _Float16 As[128 * 32];
  __shared__ __align__(16) _Float16 Bs[128 * 32];

  const _Float16* Ab = A + (size_t)b * SEQ * K + kbeg;
  const _Float16* Wb = Wt + (size_t)e * N * K + (size_t)col0 * K + kbeg;

  int e0 = t * 8, e1 = 2048 + t * 8;
  int m0 = e0 >> 5, k0e = e0 & 31;
  int m1 = e1 >> 5, k1e = e1 & 31;
  const _Float16* ga0 = Ab + (size_t)m0 * K + k0e;
  const _Float16* ga1 = Ab + (size_t)m1 * K + k1e;
  const _Float16* gb0 = Wb + (size_t)m0 * K + k0e;
  const _Float16* gb1 = Wb + (size_t)m1 * K + k1e;
  _Float16* lA0 = &As[e0]; _Float16* lA1 = &As[e1];
  _Float16* lB0 = &Bs[e0]; _Float16* lB1 = &Bs[e1];

  f32x4 acc[4][4];
#pragma unroll
  for (int i = 0; i < 4; ++i)
#pragma unroll
    for (int j = 0; j < 4; ++j) acc[i][j] = (f32x4){0.f, 0.f, 0.f, 0.f};

  for (int kk = 0; kk < Kp; kk += 32) {
    gld_lds16(ga0 + kk, lA0);
    gld_lds16(ga1 + kk, lA1);
    gld_lds16(gb0 + kk, lB0);
    gld_lds16(gb1 + kk, lB1);
    __syncthreads();
    f16x8 af[4], bf[4];
#pragma unroll
    for (int i = 0; i < 4; ++i)
      af[i] = *(const f16x8*)&As[(wr + i * 16 + l16) * 32 + quad * 8];
#pragma unroll
    for (int i = 0; i < 4; ++i)
      bf[i] = *(const f16x8*)&Bs[(wc + i * 16 + l16) * 32 + quad * 8];
#pragma unroll
    for (int i = 0; i < 4; ++i)
#pragma unroll
      for (int j = 0; j < 4; ++j)
        acc[i][j] = __builtin_amdgcn_mfma_f32_16x16x32_f16(af[i], bf[j], acc[i][j], 0, 0, 0);
    __syncthreads();
  }

  const float* bias = Ball + (size_t)e * N;

  if (OUT_F16) {
    _Float16* Ch = (_Float16*)Cv + (size_t)b * SEQ * N;
#pragma unroll
    for (int i = 0; i < 4; ++i)
#pragma unroll
      for (int j = 0; j < 4; ++j) {
        int col = col0 + wc + j * 16 + l16;
        float bv = bias[col];
#pragma unroll
        for (int r = 0; r < 4; ++r) {
          int row = wr + i * 16 + quad * 4 + r;
          float v = acc[i][j][r] + bv;
          if (GELU) v = gelu_fast(v);
          Ch[(size_t)row * N + col] = (_Float16)v;
        }
      }
  } else {
    float* Cf = (float*)Cv + (size_t)kz * NB * SEQ * N + (size_t)b * SEQ * N;
    float bscale = (kz == 0) ? 1.f : 0.f;
#pragma unroll
    for (int i = 0; i < 4; ++i)
#pragma unroll
      for (int j = 0; j < 4; ++j) {
        int col = col0 + wc + j * 16 + l16;
        float bv = bias[col] * bscale;
#pragma unroll
        for (int r = 0; r < 4; ++r) {
          int row = wr + i * 16 + quad * 4 + r;
          Cf[(size_t)row * N + col] = acc[i][j][r] + bv;
        }
      }
  }
}

// ---------------- MFMA attention: one block per (head, sample) ----------------
__global__ __launch_bounds__(256) void attn_mfma(
    const _Float16* __restrict__ QKV, const float* __restrict__ mask,
    _Float16* __restrict__ Ctx) {
  int h = blockIdx.x, b = blockIdx.y;
  int t = threadIdx.x;
  int w = t >> 6, lane = t & 63, quad = lane >> 4, l16 = lane & 15;

  __shared__ __align__(16) char smem[54784];
  _Float16* Qs = (_Float16*)smem;                 // [128][72]
  _Float16* Ks = (_Float16*)(smem + 18432);       // [128][72]
  _Float16* Ps = (_Float16*)smem;                 // [128][136]
  _Float16* Vt = (_Float16*)(smem + 36864);       // [64][136]
  float* mrow = (float*)(smem + 54272);           // [128]

  const _Float16* Qb = QKV + (size_t)b * SEQ * QKVN + h * HEADD;
  const _Float16* Kb = Qb + HDIM;
  const _Float16* Vb = Qb + 2 * HDIM;

#pragma unroll
  for (int it = 0; it < 4; ++it) {
    int chunk = t + it * 256;
    int row = chunk >> 3, c = chunk & 7;
    *(f16x8*)&Qs[row * 72 + c * 8] = *(const f16x8*)(Qb + (size_t)row * QKVN + c * 8);
    *(f16x8*)&Ks[row * 72 + c * 8] = *(const f16x8*)(Kb + (size_t)row * QKVN + c * 8);
  }
  {
    int vc = t & 7, vjp0 = t >> 3;
#pragma unroll
    for (int it = 0; it < 2; ++it) {
      int jp = vjp0 + it * 32;
      f16x8 v0 = *(const f16x8*)(Vb + (size_t)(2 * jp) * QKVN + vc * 8);
      f16x8 v1 = *(const f16x8*)(Vb + (size_t)(2 * jp + 1) * QKVN + vc * 8);
#pragma unroll
      for (int i = 0; i < 8; ++i) {
        int d = vc * 8 + i;
        unsigned ua = __builtin_bit_cast(unsigned short, (_Float16)v0[i]);
        unsigned ub = __builtin_bit_cast(unsigned short, (_Float16)v1[i]);
        ((unsigned*)Vt)[d * 68 + jp] = ua | (ub << 16);
      }
    }
  }
  if (t < SEQ) mrow[t] = mask[(size_t)b * SEQ + t];
  __syncthreads();

  int m0 = w * 32;
  f32x4 accs[2][8];
#pragma unroll
  for (int i = 0; i < 2; ++i)
#pragma unroll
    for (int j = 0; j < 8; ++j) accs[i][j] = (f32x4){0.f, 0.f, 0.f, 0.f};

#pragma unroll
  for (int ks = 0; ks < 2; ++ks) {
    int k0 = ks * 32 + quad * 8;
    f16x8 af[2], bf[8];
#pragma unroll
    for (int i = 0; i < 2; ++i)
      af[i] = *(const f16x8*)&Qs[(m0 + i * 16 + l16) * 72 + k0];
#pragma unroll
    for (int j = 0; j < 8; ++j)
      bf[j] = *(const f16x8*)&Ks[(j * 16 + l16) * 72 + k0];
#pragma unroll
    for (int i = 0; i < 2; ++i)
#pragma unroll
      for (int j = 0; j < 8; ++j)
        accs[i][j] = __builtin_amdgcn_mfma_f32_16x16x32_f16(af[i], bf[j], accs[i][j], 0, 0, 0);
  }
  __syncthreads();

  float mv[8];
#pragma unroll
  for (int j = 0; j < 8; ++j) mv[j] = mrow[j * 16 + l16];

  float linv[2][4];
#pragma unroll
  for (int i = 0; i < 2; ++i) {
#pragma unroll
    for (int j = 0; j < 8; ++j)
#pragma unroll
      for (int r = 0; r < 4; ++r)
        accs[i][j][r] = accs[i][j][r] * 0.125f + mv[j];
#pragma unroll
    for (int r = 0; r < 4; ++r) {
      float m = accs[i][0][r];
#pragma unroll
      for (int j = 1; j < 8; ++j) m = fmaxf(m, accs[i][j][r]);
      m = fmaxf(m, __shfl_xor(m, 1));
      m = fmaxf(m, __shfl_xor(m, 2));
      m = fmaxf(m, __shfl_xor(m, 4));
      m = fmaxf(m, __shfl_xor(m, 8));
      float sum = 0.f;
#pragma unroll
      for (int j = 0; j < 8; ++j) {
        float p = __expf(accs[i][j][r] - m);
        accs[i][j][r] = p;
        sum += p;
      }
      sum += __shfl_xor(sum, 1);
      sum += __shfl_xor(sum, 2);
      sum += __shfl_xor(sum, 4);
      sum += __shfl_xor(sum, 8);
      linv[i][r] = 1.f / sum;
    }
    int rowb = m0 + i * 16 + quad * 4;
#pragma unroll
    for (int j = 0; j < 8; ++j)
#pragma unroll
      for (int r = 0; r < 4; ++r)
        Ps[(rowb + r) * 136 + j * 16 + l16] = (_Float16)accs[i][j][r];
  }
  __syncthreads();

  f32x4 acco[2][4];
#pragma unroll
  for (int i = 0; i < 2; ++i)
#pragma unroll
    for (int j = 0; j < 4; ++j) acco[i][j] = (f32x4){0.f, 0.f, 0.f, 0.f};

#pragma unroll
  for (int ks = 0; ks < 4; ++ks) {
    int k0 = ks * 32 + quad * 8;
    f16x8 pa[2], vf[4];
#pragma unroll
    for (int i = 0; i < 2; ++i)
      pa[i] = *(const f16x8*)&Ps[(m0 + i * 16 + l16) * 136 + k0];
#pragma unroll
    for (int j = 0; j < 4; ++j)
      vf[j] = *(const f16x8*)&Vt[(j * 16 + l16) * 136 + k0];
#pragma unroll
    for (int i = 0; i < 2; ++i)
#pragma unroll
      for (int j = 0; j < 4; ++j)
        acco[i][j] = __builtin_amdgcn_mfma_f32_16x16x32_f16(pa[i], vf[j], acco[i][j], 0, 0, 0);
  }

  _Float16* Cb = Ctx + (size_t)b * SEQ * HDIM + h * HEADD;
#pragma unroll
  for (int i = 0; i < 2; ++i)
#pragma unroll
    for (int j = 0; j < 4; ++j)
#pragma unroll
      for (int r = 0; r < 4; ++r) {
        int row = m0 + i * 16 + quad * 4 + r;
        int d = j * 16 + l16;
        Cb[(size_t)row * HDIM + d] = (_Float16)(acco[i][j][r] * linv[i][r]);
      }
}

// ---------------- residual + NP partials + layernorm ---------------------------
template <int NP>
__global__ __launch_bounds__(256) void resid_ln_kernel(
    const float* __restrict__ X, const float* __restrict__ P0,
    const float* __restrict__ P1,
    const float* __restrict__ Gall, const float* __restrict__ Ball,
    const int* __restrict__ eid, float* __restrict__ Out,
    _Float16* __restrict__ Out16) {
  int row = blockIdx.x, b = blockIdx.y, t = threadIdx.x;
  int e = eid[b];
  size_t off = ((size_t)b * SEQ + row) * HDIM;
  const float* x = X + off;
  const float* p0 = P0 + off;
  const float* p1 = (NP > 1) ? P1 + off : nullptr;
  float* o = Out + off;
  const float* g = Gall + (size_t)e * HDIM;
  const float* bb = Ball + (size_t)e * HDIM;

  __shared__ float buf[HDIM];
  __shared__ float red[256];

  float s = 0.f;
  for (int h = t; h < HDIM; h += 256) {
    float v = x[h] + p0[h];
    if (NP > 1) v += p1[h];
    buf[h] = v;
    s += v;
  }
  red[t] = s;
  __syncthreads();
  for (int off2 = 128; off2 > 0; off2 >>= 1) {
    if (t < off2) red[t] += red[t + off2];
    __syncthreads();
  }
  float mean = red[0] * (1.0f / HDIM);
  __syncthreads();

  float s2 = 0.f;
  for (int h = t; h < HDIM; h += 256) {
    float d = buf[h] - mean;
    s2 += d * d;
  }
  red[t] = s2;
  __syncthreads();
  for (int off2 = 128; off2 > 0; off2 >>= 1) {
    if (t < off2) red[t] += red[t + off2];
    __syncthreads();
  }
  float var = red[0] * (1.0f / HDIM);
  float rs = rsqrtf(var + 1e-12f);

  for (int h = t; h < HDIM; h += 256) {
    float v = (buf[h] - mean) * rs * g[h] + bb[h];
    o[h] = v;
    if (Out16) Out16[off + h] = (_Float16)v;
  }
}

// ------------------------------------------------------------------------------
extern "C" void kernel_launch(void* const* d_in, const int* in_sizes, int n_in,
                              void* d_out, int out_size, void* d_ws, size_t ws_size,
                              hipStream_t stream) {
  const float* hs   = (const float*)d_in[0];
  const float* mask = (const float*)d_in[1];
  const float* cen  = (const float*)d_in[2];
  const float* wq = (const float*)d_in[3];
  const float* wk = (const float*)d_in[4];
  const float* wv = (const float*)d_in[5];
  const float* wo = (const float*)d_in[6];
  const float* bq = (const float*)d_in[7];
  const float* bk = (const float*)d_in[8];
  const float* bv = (const float*)d_in[9];
  const float* bo = (const float*)d_in[10];
  const float* ln1g = (const float*)d_in[11];
  const float* ln1b = (const float*)d_in[12];
  const float* w1 = (const float*)d_in[13];
  const float* b1 = (const float*)d_in[14];
  const float* w2 = (const float*)d_in[15];
  const float* b2 = (const float*)d_in[16];
  const float* ln2g = (const float*)d_in[17];
  const float* ln2b = (const float*)d_in[18];
  float* out = (float*)d_out;

  const size_t sh = (size_t)SEQ * HDIM;

  char* p = (char*)d_ws;
  int* eid = (int*)p;                 p += 256;
  int* order = (int*)p;               p += 256;
  int* ord_eid = (int*)p;             p += 256;
  float* bqkv = (float*)p;            p += (size_t)NEXP * QKVN * 4;
  _Float16* Wqkvt = (_Float16*)p;     p += (size_t)NEXP * QKVN * HDIM * 2;
  _Float16* Wot = (_Float16*)p;       p += (size_t)NEXP * HDIM * HDIM * 2;
  _Float16* W1t = (_Float16*)p;       p += (size_t)NEXP * FFDIM * HDIM * 2;
  _Float16* W2t = (_Float16*)p;       p += (size_t)NEXP * HDIM * FFDIM * 2;
  _Float16* x16 = (_Float16*)p;       p += (size_t)NB * sh * 2;

  char* region = p;                   p += (size_t)NB * SEQ * QKVN * 2;
  _Float16* ctx16 = (_Float16*)p;     p += (size_t)NB * sh * 2;
  float* aof = (float*)p;             p += (size_t)NB * sh * 4;
  _Float16* ao16 = (_Float16*)p;      p += (size_t)NB * sh * 2;
  char* ffreg = p;                    p += (size_t)NB * SEQ * FFDIM * 2;

  float* woparts = (float*)ffreg;
  float* w2parts = (float*)region;
  _Float16* ff16 = (_Float16*)ffreg;

  // 1. routing + hs->f16 (fused)
  route_cvt_kernel<<<NB, 256, 0, stream>>>(hs, cen, eid, x16);
  // 2. all weight transposes + bias concat + expert sort (single launch)
  prep_weights<<<dim3(6949, NEXP), 256, 0, stream>>>(
      wq, wk, wv, wo, w1, w2, bq, bk, bv,
      Wqkvt, Wot, W1t, W2t, bqkv, eid, order, ord_eid);
  // 3. QKV fused -> region (f16)
  gemm_mfma<1, 0, 1><<<dim3((QKVN / 128) * NB, 1), 256, 0, stream>>>(
      x16, Wqkvt, bqkv, order, ord_eid, region, HDIM, QKVN);
  // 4. attention -> ctx16
  attn_mfma<<<dim3(NHEAD, NB), 256, 0, stream>>>(
      (const _Float16*)region, mask, ctx16);
  // 5. wo split-K=2 -> woparts (ffreg)
  gemm_mfma<0, 0, 2><<<dim3((HDIM / 128) * NB, 2), 256, 0, stream>>>(
      ctx16, Wot, bo, order, ord_eid, woparts, HDIM, HDIM);
  // 6. LN1 = LN(hs + p0 + p1) -> aof + ao16
  resid_ln_kernel<2><<<dim3(SEQ, NB), 256, 0, stream>>>(
      hs, woparts, woparts + (size_t)NB * sh, ln1g, ln1b, eid, aof, ao16);
  // 7. w1 + fast GELU -> ff16 (overwrites woparts, already consumed)
  gemm_mfma<1, 1, 1><<<dim3((FFDIM / 128) * NB, 1), 256, 0, stream>>>(
      ao16, W1t, b1, order, ord_eid, ff16, HDIM, FFDIM);
  // 8. w2 split-K=2 -> w2parts (region; qkv+ctx dead)
  gemm_mfma<0, 0, 2><<<dim3((HDIM / 128) * NB, 2), 256, 0, stream>>>(
      ff16, W2t, b2, order, ord_eid, w2parts, FFDIM, HDIM);
  // 9. LN2 -> out
  resid_ln_kernel<2><<<dim3(SEQ, NB), 256, 0, stream>>>(
      aof, w2parts, w2parts + (size_t)NB * sh, ln2g, ln2b, eid, out,
      (_Float16*)nullptr);
}

// Round 7
// 473.328 us; speedup vs baseline: 1.3275x; 1.0197x over previous
//
#include <hip/hip_runtime.h>
#include <hip/hip_bf16.h>
#include <math.h>

#define HDIM 768
#define NHEAD 12
#define HEADD 64
#define FFDIM 3072
#define NEXP 4
#define SEQ 128
#define NB 64
#define QKVN 2304

typedef __attribute__((ext_vector_type(8))) _Float16 f16x8;
typedef __attribute__((ext_vector_type(4))) _Float16 f16x4;
typedef __attribute__((ext_vector_type(4))) float f32x4;

// gelu_tanh(x) = x * sigmoid(1.5957691*x*(1+0.044715x^2)) — exact rewrite
__device__ __forceinline__ float gelu_fast(float x) {
  float t = -1.5957691216057308f * x * __builtin_fmaf(0.044715f * x, x, 1.0f);
  return x * __builtin_amdgcn_rcpf(1.0f + __expf(t));
}

__device__ __forceinline__ void gld_lds16(const void* g, void* l) {
  __builtin_amdgcn_global_load_lds(
      (const __attribute__((address_space(1))) unsigned int*)g,
      (__attribute__((address_space(3))) unsigned int*)l, 16, 0, 0);
}

// ---------------- routing + fp32->f16 conversion (fused) ----------------------
__global__ __launch_bounds__(256) void route_cvt_kernel(
    const float* __restrict__ hs, const float* __restrict__ centers,
    int* __restrict__ eid, _Float16* __restrict__ x16) {
  int b = blockIdx.x, t = threadIdx.x;
  __shared__ float hp[HDIM];
  __shared__ float dist[NEXP];
  const float* xb = hs + (size_t)b * SEQ * HDIM;
  _Float16* ob = x16 + (size_t)b * SEQ * HDIM;

  if (t < 192) {
    float p0 = 0.f, p1 = 0.f, p2 = 0.f, p3 = 0.f;
    for (int sq = 0; sq < SEQ; ++sq) {
      float4 v = ((const float4*)(xb + (size_t)sq * HDIM))[t];
      p0 += v.x; p1 += v.y; p2 += v.z; p3 += v.w;
      f16x4 h = {(_Float16)v.x, (_Float16)v.y, (_Float16)v.z, (_Float16)v.w};
      *(f16x4*)(ob + (size_t)sq * HDIM + t * 4) = h;
    }
    hp[t * 4 + 0] = p0 * (1.0f / SEQ);
    hp[t * 4 + 1] = p1 * (1.0f / SEQ);
    hp[t * 4 + 2] = p2 * (1.0f / SEQ);
    hp[t * 4 + 3] = p3 * (1.0f / SEQ);
  }
  if (t < NEXP) dist[t] = 0.f;
  __syncthreads();

  float pe[NEXP] = {0.f, 0.f, 0.f, 0.f};
  for (int h = t; h < HDIM; h += 256) {
    float v = hp[h];
#pragma unroll
    for (int e = 0; e < NEXP; ++e) {
      float d = v - centers[e * HDIM + h];
      pe[e] += d * d;
    }
  }
#pragma unroll
  for (int e = 0; e < NEXP; ++e) atomicAdd(&dist[e], pe[e]);
  __syncthreads();
  if (t == 0) {
    int best = 0; float bv = dist[0];
    for (int e = 1; e < NEXP; ++e) if (dist[e] < bv) { bv = dist[e]; best = e; }
    eid[b] = best;
  }
}

// ---------------- ALL weight prep in one launch -------------------------------
__device__ __forceinline__ void tr_tile(const float* __restrict__ ip,
                                        _Float16* __restrict__ op,
                                        int K, int N, int nb, int kb,
                                        float (*tile)[33], int t) {
  int tx = t & 31, ty = t >> 5;
  for (int i = ty; i < 32; i += 8)
    tile[i][tx] = ip[(size_t)(kb + i) * N + nb + tx];
  __syncthreads();
  for (int i = ty; i < 32; i += 8)
    op[(size_t)(nb + i) * K + kb + tx] = (_Float16)tile[tx][i];
}

__global__ __launch_bounds__(256) void prep_weights(
    const float* __restrict__ wq, const float* __restrict__ wk,
    const float* __restrict__ wv, const float* __restrict__ wo,
    const float* __restrict__ w1, const float* __restrict__ w2,
    const float* __restrict__ bq, const float* __restrict__ bk,
    const float* __restrict__ bv,
    _Float16* __restrict__ Wqkvt, _Float16* __restrict__ Wot,
    _Float16* __restrict__ W1t, _Float16* __restrict__ W2t,
    float* __restrict__ bqkv, const int* __restrict__ eid,
    int* __restrict__ order, int* __restrict__ ord_eid) {
  __shared__ float tile[32][33];
  int x = blockIdx.x, e = blockIdx.y, t = threadIdx.x;

  if (x < 1728) {
    int which = x / 576, local = x % 576;
    const float* src = (which == 0) ? wq : (which == 1) ? wk : wv;
    tr_tile(src + (size_t)e * HDIM * HDIM,
            Wqkvt + (size_t)which * HDIM * HDIM + (size_t)e * QKVN * HDIM,
            HDIM, HDIM, (local % 24) * 32, (local / 24) * 32, tile, t);
  } else if (x < 2304) {
    int local = x - 1728;
    tr_tile(wo + (size_t)e * HDIM * HDIM, Wot + (size_t)e * HDIM * HDIM,
            HDIM, HDIM, (local % 24) * 32, (local / 24) * 32, tile, t);
  } else if (x < 4608) {
    int local = x - 2304;
    tr_tile(w1 + (size_t)e * HDIM * FFDIM, W1t + (size_t)e * FFDIM * HDIM,
            HDIM, FFDIM, (local % 96) * 32, (local / 96) * 32, tile, t);
  } else if (x < 6912) {
    int local = x - 4608;
    tr_tile(w2 + (size_t)e * FFDIM * HDIM, W2t + (size_t)e * HDIM * FFDIM,
            FFDIM, HDIM, (local % 24) * 32, (local / 24) * 32, tile, t);
  } else if (x < 6948) {
    if (e == 0) {
      int i = (x - 6912) * 256 + t;
      if (i < NEXP * QKVN) {
        int ee = i / QKVN, n = i % QKVN;
        float v = (n < HDIM) ? bq[ee * HDIM + n]
                : (n < 2 * HDIM) ? bk[ee * HDIM + n - HDIM]
                                 : bv[ee * HDIM + n - 2 * HDIM];
        bqkv[i] = v;
      }
    }
  } else {
    if (e == 0 && t == 0) {
      int n = 0;
      for (int ee = 0; ee < NEXP; ++ee)
        for (int b = 0; b < NB; ++b)
          if (eid[b] == ee) { order[n] = b; ord_eid[n] = ee; n++; }
    }
  }
}

// ---------------- MFMA GEMM: compile-time K -> fully unrolled K-loop ----------
// XCD-pinned swizzle + optional split-K. All kk offsets constant-fold into
// global_load_lds immediates (r6: K-loop addr VALU was pacing the MFMA pipe).
template <int OUT_F16, int GELU, int KDIM, int SPLITK>
__global__ __launch_bounds__(256) void gemm_mfma(
    const _Float16* __restrict__ A, const _Float16* __restrict__ Wt,
    const float* __restrict__ Ball, const int* __restrict__ order,
    const int* __restrict__ ord_eid, void* __restrict__ Cv, int N) {
  constexpr int K = KDIM;
  constexpr int Kp = KDIM / SPLITK;
  int GX = N >> 7;
  int L = blockIdx.x;
  int low3 = L & 7, Mq = L >> 3;
  int x = Mq % GX, zhi = Mq / GX;
  int z = zhi * 8 + low3;
  int b = order[z];
  int e = ord_eid[z];
  int col0 = x * 128;
  int kz = blockIdx.y;
  int kbeg = kz * Kp;

  int t = threadIdx.x;
  int lane = t & 63, w = t >> 6;
  int quad = lane >> 4, l16 = lane & 15;
  int wr = (w >> 1) * 64, wc = (w & 1) * 64;

  __shared__ __align__(16) _Float16 As[128 * 32];
  __shared__ __align__(16) _Float16 Bs[128 * 32];

  const _Float16* Ab = A + (size_t)b * SEQ * K + kbeg;
  const _Float16* Wb = Wt + (size_t)e * N * K + (size_t)col0 * K + kbeg;

  int e0 = t * 8, e1 = 2048 + t * 8;
  int m0 = e0 >> 5, k0e = e0 & 31;
  int m1 = e1 >> 5, k1e = e1 & 31;
  const _Float16* ga0 = Ab + (size_t)m0 * K + k0e;
  const _Float16* ga1 = Ab + (size_t)m1 * K + k1e;
  const _Float16* gb0 = Wb + (size_t)m0 * K + k0e;
  const _Float16* gb1 = Wb + (size_t)m1 * K + k1e;
  _Float16* lA0 = &As[e0]; _Float16* lA1 = &As[e1];
  _Float16* lB0 = &Bs[e0]; _Float16* lB1 = &Bs[e1];

  f32x4 acc[4][4];
#pragma unroll
  for (int i = 0; i < 4; ++i)
#pragma unroll
    for (int j = 0; j < 4; ++j) acc[i][j] = (f32x4){0.f, 0.f, 0.f, 0.f};

#pragma unroll
  for (int kk = 0; kk < Kp; kk += 32) {
    gld_lds16(ga0 + kk, lA0);
    gld_lds16(ga1 + kk, lA1);
    gld_lds16(gb0 + kk, lB0);
    gld_lds16(gb1 + kk, lB1);
    __syncthreads();
    f16x8 af[4], bf[4];
#pragma unroll
    for (int i = 0; i < 4; ++i)
      af[i] = *(const f16x8*)&As[(wr + i * 16 + l16) * 32 + quad * 8];
#pragma unroll
    for (int i = 0; i < 4; ++i)
      bf[i] = *(const f16x8*)&Bs[(wc + i * 16 + l16) * 32 + quad * 8];
#pragma unroll
    for (int i = 0; i < 4; ++i)
#pragma unroll
      for (int j = 0; j < 4; ++j)
        acc[i][j] = __builtin_amdgcn_mfma_f32_16x16x32_f16(af[i], bf[j], acc[i][j], 0, 0, 0);
    __syncthreads();
  }

  const float* bias = Ball + (size_t)e * N;

  if (OUT_F16) {
    _Float16* Ch = (_Float16*)Cv + (size_t)b * SEQ * N;
#pragma unroll
    for (int i = 0; i < 4; ++i)
#pragma unroll
      for (int j = 0; j < 4; ++j) {
        int col = col0 + wc + j * 16 + l16;
        float bv = bias[col];
#pragma unroll
        for (int r = 0; r < 4; ++r) {
          int row = wr + i * 16 + quad * 4 + r;
          float v = acc[i][j][r] + bv;
          if (GELU) v = gelu_fast(v);
          Ch[(size_t)row * N + col] = (_Float16)v;
        }
      }
  } else {
    float* Cf = (float*)Cv + (size_t)kz * NB * SEQ * N + (size_t)b * SEQ * N;
    float bscale = (kz == 0) ? 1.f : 0.f;
#pragma unroll
    for (int i = 0; i < 4; ++i)
#pragma unroll
      for (int j = 0; j < 4; ++j) {
        int col = col0 + wc + j * 16 + l16;
        float bv = bias[col] * bscale;
#pragma unroll
        for (int r = 0; r < 4; ++r) {
          int row = wr + i * 16 + quad * 4 + r;
          Cf[(size_t)row * N + col] = acc[i][j][r] + bv;
        }
      }
  }
}

// ---------------- MFMA attention: one block per (head, sample) ----------------
__global__ __launch_bounds__(256) void attn_mfma(
    const _Float16* __restrict__ QKV, const float* __restrict__ mask,
    _Float16* __restrict__ Ctx) {
  int h = blockIdx.x, b = blockIdx.y;
  int t = threadIdx.x;
  int w = t >> 6, lane = t & 63, quad = lane >> 4, l16 = lane & 15;

  __shared__ __align__(16) char smem[54784];
  _Float16* Qs = (_Float16*)smem;                 // [128][72]
  _Float16* Ks = (_Float16*)(smem + 18432);       // [128][72]
  _Float16* Ps = (_Float16*)smem;                 // [128][136]
  _Float16* Vt = (_Float16*)(smem + 36864);       // [64][136]
  float* mrow = (float*)(smem + 54272);           // [128]

  const _Float16* Qb = QKV + (size_t)b * SEQ * QKVN + h * HEADD;
  const _Float16* Kb = Qb + HDIM;
  const _Float16* Vb = Qb + 2 * HDIM;

#pragma unroll
  for (int it = 0; it < 4; ++it) {
    int chunk = t + it * 256;
    int row = chunk >> 3, c = chunk & 7;
    *(f16x8*)&Qs[row * 72 + c * 8] = *(const f16x8*)(Qb + (size_t)row * QKVN + c * 8);
    *(f16x8*)&Ks[row * 72 + c * 8] = *(const f16x8*)(Kb + (size_t)row * QKVN + c * 8);
  }
  {
    int vc = t & 7, vjp0 = t >> 3;
#pragma unroll
    for (int it = 0; it < 2; ++it) {
      int jp = vjp0 + it * 32;
      f16x8 v0 = *(const f16x8*)(Vb + (size_t)(2 * jp) * QKVN + vc * 8);
      f16x8 v1 = *(const f16x8*)(Vb + (size_t)(2 * jp + 1) * QKVN + vc * 8);
#pragma unroll
      for (int i = 0; i < 8; ++i) {
        int d = vc * 8 + i;
        unsigned ua = __builtin_bit_cast(unsigned short, (_Float16)v0[i]);
        unsigned ub = __builtin_bit_cast(unsigned short, (_Float16)v1[i]);
        ((unsigned*)Vt)[d * 68 + jp] = ua | (ub << 16);
      }
    }
  }
  if (t < SEQ) mrow[t] = mask[(size_t)b * SEQ + t];
  __syncthreads();

  int m0 = w * 32;
  f32x4 accs[2][8];
#pragma unroll
  for (int i = 0; i < 2; ++i)
#pragma unroll
    for (int j = 0; j < 8; ++j) accs[i][j] = (f32x4){0.f, 0.f, 0.f, 0.f};

#pragma unroll
  for (int ks = 0; ks < 2; ++ks) {
    int k0 = ks * 32 + quad * 8;
    f16x8 af[2], bf[8];
#pragma unroll
    for (int i = 0; i < 2; ++i)
      af[i] = *(const f16x8*)&Qs[(m0 + i * 16 + l16) * 72 + k0];
#pragma unroll
    for (int j = 0; j < 8; ++j)
      bf[j] = *(const f16x8*)&Ks[(j * 16 + l16) * 72 + k0];
#pragma unroll
    for (int i = 0; i < 2; ++i)
#pragma unroll
      for (int j = 0; j < 8; ++j)
        accs[i][j] = __builtin_amdgcn_mfma_f32_16x16x32_f16(af[i], bf[j], accs[i][j], 0, 0, 0);
  }
  __syncthreads();

  float mv[8];
#pragma unroll
  for (int j = 0; j < 8; ++j) mv[j] = mrow[j * 16 + l16];

  float linv[2][4];
#pragma unroll
  for (int i = 0; i < 2; ++i) {
#pragma unroll
    for (int j = 0; j < 8; ++j)
#pragma unroll
      for (int r = 0; r < 4; ++r)
        accs[i][j][r] = accs[i][j][r] * 0.125f + mv[j];
#pragma unroll
    for (int r = 0; r < 4; ++r) {
      float m = accs[i][0][r];
#pragma unroll
      for (int j = 1; j < 8; ++j) m = fmaxf(m, accs[i][j][r]);
      m = fmaxf(m, __shfl_xor(m, 1));
      m = fmaxf(m, __shfl_xor(m, 2));
      m = fmaxf(m, __shfl_xor(m, 4));
      m = fmaxf(m, __shfl_xor(m, 8));
      float sum = 0.f;
#pragma unroll
      for (int j = 0; j < 8; ++j) {
        float p = __expf(accs[i][j][r] - m);
        accs[i][j][r] = p;
        sum += p;
      }
      sum += __shfl_xor(sum, 1);
      sum += __shfl_xor(sum, 2);
      sum += __shfl_xor(sum, 4);
      sum += __shfl_xor(sum, 8);
      linv[i][r] = 1.f / sum;
    }
    int rowb = m0 + i * 16 + quad * 4;
#pragma unroll
    for (int j = 0; j < 8; ++j)
#pragma unroll
      for (int r = 0; r < 4; ++r)
        Ps[(rowb + r) * 136 + j * 16 + l16] = (_Float16)accs[i][j][r];
  }
  __syncthreads();

  f32x4 acco[2][4];
#pragma unroll
  for (int i = 0; i < 2; ++i)
#pragma unroll
    for (int j = 0; j < 4; ++j) acco[i][j] = (f32x4){0.f, 0.f, 0.f, 0.f};

#pragma unroll
  for (int ks = 0; ks < 4; ++ks) {
    int k0 = ks * 32 + quad * 8;
    f16x8 pa[2], vf[4];
#pragma unroll
    for (int i = 0; i < 2; ++i)
      pa[i] = *(const f16x8*)&Ps[(m0 + i * 16 + l16) * 136 + k0];
#pragma unroll
    for (int j = 0; j < 4; ++j)
      vf[j] = *(const f16x8*)&Vt[(j * 16 + l16) * 136 + k0];
#pragma unroll
    for (int i = 0; i < 2; ++i)
#pragma unroll
      for (int j = 0; j < 4; ++j)
        acco[i][j] = __builtin_amdgcn_mfma_f32_16x16x32_f16(pa[i], vf[j], acco[i][j], 0, 0, 0);
  }

  _Float16* Cb = Ctx + (size_t)b * SEQ * HDIM + h * HEADD;
#pragma unroll
  for (int i = 0; i < 2; ++i)
#pragma unroll
    for (int j = 0; j < 4; ++j)
#pragma unroll
      for (int r = 0; r < 4; ++r) {
        int row = m0 + i * 16 + quad * 4 + r;
        int d = j * 16 + l16;
        Cb[(size_t)row * HDIM + d] = (_Float16)(acco[i][j][r] * linv[i][r]);
      }
}

// ---------------- residual + NP partials + layernorm ---------------------------
template <int NP>
__global__ __launch_bounds__(256) void resid_ln_kernel(
    const float* __restrict__ X, const float* __restrict__ P0,
    const float* __restrict__ P1,
    const float* __restrict__ Gall, const float* __restrict__ Ball,
    const int* __restrict__ eid, float* __restrict__ Out,
    _Float16* __restrict__ Out16) {
  int row = blockIdx.x, b = blockIdx.y, t = threadIdx.x;
  int e = eid[b];
  size_t off = ((size_t)b * SEQ + row) * HDIM;
  const float* x = X + off;
  const float* p0 = P0 + off;
  const float* p1 = (NP > 1) ? P1 + off : nullptr;
  float* o = Out + off;
  const float* g = Gall + (size_t)e * HDIM;
  const float* bb = Ball + (size_t)e * HDIM;

  __shared__ float buf[HDIM];
  __shared__ float red[256];

  float s = 0.f;
  for (int h = t; h < HDIM; h += 256) {
    float v = x[h] + p0[h];
    if (NP > 1) v += p1[h];
    buf[h] = v;
    s += v;
  }
  red[t] = s;
  __syncthreads();
  for (int off2 = 128; off2 > 0; off2 >>= 1) {
    if (t < off2) red[t] += red[t + off2];
    __syncthreads();
  }
  float mean = red[0] * (1.0f / HDIM);
  __syncthreads();

  float s2 = 0.f;
  for (int h = t; h < HDIM; h += 256) {
    float d = buf[h] - mean;
    s2 += d * d;
  }
  red[t] = s2;
  __syncthreads();
  for (int off2 = 128; off2 > 0; off2 >>= 1) {
    if (t < off2) red[t] += red[t + off2];
    __syncthreads();
  }
  float var = red[0] * (1.0f / HDIM);
  float rs = rsqrtf(var + 1e-12f);

  for (int h = t; h < HDIM; h += 256) {
    float v = (buf[h] - mean) * rs * g[h] + bb[h];
    o[h] = v;
    if (Out16) Out16[off + h] = (_Float16)v;
  }
}

// ------------------------------------------------------------------------------
extern "C" void kernel_launch(void* const* d_in, const int* in_sizes, int n_in,
                              void* d_out, int out_size, void* d_ws, size_t ws_size,
                              hipStream_t stream) {
  const float* hs   = (const float*)d_in[0];
  const float* mask = (const float*)d_in[1];
  const float* cen  = (const float*)d_in[2];
  const float* wq = (const float*)d_in[3];
  const float* wk = (const float*)d_in[4];
  const float* wv = (const float*)d_in[5];
  const float* wo = (const float*)d_in[6];
  const float* bq = (const float*)d_in[7];
  const float* bk = (const float*)d_in[8];
  const float* bv = (const float*)d_in[9];
  const float* bo = (const float*)d_in[10];
  const float* ln1g = (const float*)d_in[11];
  const float* ln1b = (const float*)d_in[12];
  const float* w1 = (const float*)d_in[13];
  const float* b1 = (const float*)d_in[14];
  const float* w2 = (const float*)d_in[15];
  const float* b2 = (const float*)d_in[16];
  const float* ln2g = (const float*)d_in[17];
  const float* ln2b = (const float*)d_in[18];
  float* out = (float*)d_out;

  const size_t sh = (size_t)SEQ * HDIM;

  char* p = (char*)d_ws;
  int* eid = (int*)p;                 p += 256;
  int* order = (int*)p;               p += 256;
  int* ord_eid = (int*)p;             p += 256;
  float* bqkv = (float*)p;            p += (size_t)NEXP * QKVN * 4;
  _Float16* Wqkvt = (_Float16*)p;     p += (size_t)NEXP * QKVN * HDIM * 2;
  _Float16* Wot = (_Float16*)p;       p += (size_t)NEXP * HDIM * HDIM * 2;
  _Float16* W1t = (_Float16*)p;       p += (size_t)NEXP * FFDIM * HDIM * 2;
  _Float16* W2t = (_Float16*)p;       p += (size_t)NEXP * HDIM * FFDIM * 2;
  _Float16* x16 = (_Float16*)p;       p += (size_t)NB * sh * 2;

  char* region = p;                   p += (size_t)NB * SEQ * QKVN * 2;
  _Float16* ctx16 = (_Float16*)p;     p += (size_t)NB * sh * 2;
  float* aof = (float*)p;             p += (size_t)NB * sh * 4;
  _Float16* ao16 = (_Float16*)p;      p += (size_t)NB * sh * 2;
  char* ffreg = p;                    p += (size_t)NB * SEQ * FFDIM * 2;

  float* woparts = (float*)ffreg;
  float* w2parts = (float*)region;
  _Float16* ff16 = (_Float16*)ffreg;

  // 1. routing + hs->f16
  route_cvt_kernel<<<NB, 256, 0, stream>>>(hs, cen, eid, x16);
  // 2. weight prep (single launch)
  prep_weights<<<dim3(6949, NEXP), 256, 0, stream>>>(
      wq, wk, wv, wo, w1, w2, bq, bk, bv,
      Wqkvt, Wot, W1t, W2t, bqkv, eid, order, ord_eid);
  // 3. QKV fused -> region (f16)
  gemm_mfma<1, 0, HDIM, 1><<<dim3((QKVN / 128) * NB, 1), 256, 0, stream>>>(
      x16, Wqkvt, bqkv, order, ord_eid, region, QKVN);
  // 4. attention -> ctx16
  attn_mfma<<<dim3(NHEAD, NB), 256, 0, stream>>>(
      (const _Float16*)region, mask, ctx16);
  // 5. wo split-K=2 -> woparts (ffreg)
  gemm_mfma<0, 0, HDIM, 2><<<dim3((HDIM / 128) * NB, 2), 256, 0, stream>>>(
      ctx16, Wot, bo, order, ord_eid, woparts, HDIM);
  // 6. LN1
  resid_ln_kernel<2><<<dim3(SEQ, NB), 256, 0, stream>>>(
      hs, woparts, woparts + (size_t)NB * sh, ln1g, ln1b, eid, aof, ao16);
  // 7. w1 + fast GELU -> ff16
  gemm_mfma<1, 1, HDIM, 1><<<dim3((FFDIM / 128) * NB, 1), 256, 0, stream>>>(
      ao16, W1t, b1, order, ord_eid, ff16, FFDIM);
  // 8. w2 split-K=2 -> w2parts
  gemm_mfma<0, 0, FFDIM, 2><<<dim3((HDIM / 128) * NB, 2), 256, 0, stream>>>(
      ff16, W2t, b2, order, ord_eid, w2parts, HDIM);
  // 9. LN2 -> out
  resid_ln_kernel<2><<<dim3(SEQ, NB), 256, 0, stream>>>(
      aof, w2parts, w2parts + (size_t)NB * sh, ln2g, ln2b, eid, out,
      (_Float16*)nullptr);
}

// Round 8
// 467.501 us; speedup vs baseline: 1.3441x; 1.0125x over previous
//
#include <hip/hip_runtime.h>
#include <hip/hip_bf16.h>
#include <math.h>

#define HDIM 768
#define NHEAD 12
#define HEADD 64
#define FFDIM 3072
#define NEXP 4
#define SEQ 128
#define NB 64
#define QKVN 2304

typedef __attribute__((ext_vector_type(8))) _Float16 f16x8;
typedef __attribute__((ext_vector_type(4))) _Float16 f16x4;
typedef __attribute__((ext_vector_type(4))) float f32x4;

// gelu_tanh(x) = x * sigmoid(1.5957691*x*(1+0.044715x^2)) — exact rewrite
__device__ __forceinline__ float gelu_fast(float x) {
  float t = -1.5957691216057308f * x * __builtin_fmaf(0.044715f * x, x, 1.0f);
  return x * __builtin_amdgcn_rcpf(1.0f + __expf(t));
}

__device__ __forceinline__ void gld_lds16(const void* g, void* l) {
  __builtin_amdgcn_global_load_lds(
      (const __attribute__((address_space(1))) unsigned int*)g,
      (__attribute__((address_space(3))) unsigned int*)l, 16, 0, 0);
}

// ---------------- routing + fp32->f16 conversion (fused) ----------------------
__global__ __launch_bounds__(256) void route_cvt_kernel(
    const float* __restrict__ hs, const float* __restrict__ centers,
    int* __restrict__ eid, _Float16* __restrict__ x16) {
  int b = blockIdx.x, t = threadIdx.x;
  __shared__ float hp[HDIM];
  __shared__ float dist[NEXP];
  const float* xb = hs + (size_t)b * SEQ * HDIM;
  _Float16* ob = x16 + (size_t)b * SEQ * HDIM;

  if (t < 192) {
    float p0 = 0.f, p1 = 0.f, p2 = 0.f, p3 = 0.f;
    for (int sq = 0; sq < SEQ; ++sq) {
      float4 v = ((const float4*)(xb + (size_t)sq * HDIM))[t];
      p0 += v.x; p1 += v.y; p2 += v.z; p3 += v.w;
      f16x4 h = {(_Float16)v.x, (_Float16)v.y, (_Float16)v.z, (_Float16)v.w};
      *(f16x4*)(ob + (size_t)sq * HDIM + t * 4) = h;
    }
    hp[t * 4 + 0] = p0 * (1.0f / SEQ);
    hp[t * 4 + 1] = p1 * (1.0f / SEQ);
    hp[t * 4 + 2] = p2 * (1.0f / SEQ);
    hp[t * 4 + 3] = p3 * (1.0f / SEQ);
  }
  if (t < NEXP) dist[t] = 0.f;
  __syncthreads();

  float pe[NEXP] = {0.f, 0.f, 0.f, 0.f};
  for (int h = t; h < HDIM; h += 256) {
    float v = hp[h];
#pragma unroll
    for (int e = 0; e < NEXP; ++e) {
      float d = v - centers[e * HDIM + h];
      pe[e] += d * d;
    }
  }
#pragma unroll
  for (int e = 0; e < NEXP; ++e) atomicAdd(&dist[e], pe[e]);
  __syncthreads();
  if (t == 0) {
    int best = 0; float bv = dist[0];
    for (int e = 1; e < NEXP; ++e) if (dist[e] < bv) { bv = dist[e]; best = e; }
    eid[b] = best;
  }
}

// ---------------- ALL weight prep in one launch -------------------------------
__device__ __forceinline__ void tr_tile(const float* __restrict__ ip,
                                        _Float16* __restrict__ op,
                                        int K, int N, int nb, int kb,
                                        float (*tile)[33], int t) {
  int tx = t & 31, ty = t >> 5;
  for (int i = ty; i < 32; i += 8)
    tile[i][tx] = ip[(size_t)(kb + i) * N + nb + tx];
  __syncthreads();
  for (int i = ty; i < 32; i += 8)
    op[(size_t)(nb + i) * K + kb + tx] = (_Float16)tile[tx][i];
}

__global__ __launch_bounds__(256) void prep_weights(
    const float* __restrict__ wq, const float* __restrict__ wk,
    const float* __restrict__ wv, const float* __restrict__ wo,
    const float* __restrict__ w1, const float* __restrict__ w2,
    const float* __restrict__ bq, const float* __restrict__ bk,
    const float* __restrict__ bv,
    _Float16* __restrict__ Wqkvt, _Float16* __restrict__ Wot,
    _Float16* __restrict__ W1t, _Float16* __restrict__ W2t,
    float* __restrict__ bqkv, const int* __restrict__ eid,
    int* __restrict__ order, int* __restrict__ ord_eid) {
  __shared__ float tile[32][33];
  int x = blockIdx.x, e = blockIdx.y, t = threadIdx.x;

  if (x < 1728) {
    int which = x / 576, local = x % 576;
    const float* src = (which == 0) ? wq : (which == 1) ? wk : wv;
    tr_tile(src + (size_t)e * HDIM * HDIM,
            Wqkvt + (size_t)which * HDIM * HDIM + (size_t)e * QKVN * HDIM,
            HDIM, HDIM, (local % 24) * 32, (local / 24) * 32, tile, t);
  } else if (x < 2304) {
    int local = x - 1728;
    tr_tile(wo + (size_t)e * HDIM * HDIM, Wot + (size_t)e * HDIM * HDIM,
            HDIM, HDIM, (local % 24) * 32, (local / 24) * 32, tile, t);
  } else if (x < 4608) {
    int local = x - 2304;
    tr_tile(w1 + (size_t)e * HDIM * FFDIM, W1t + (size_t)e * FFDIM * HDIM,
            HDIM, FFDIM, (local % 96) * 32, (local / 96) * 32, tile, t);
  } else if (x < 6912) {
    int local = x - 4608;
    tr_tile(w2 + (size_t)e * FFDIM * HDIM, W2t + (size_t)e * HDIM * FFDIM,
            FFDIM, HDIM, (local % 24) * 32, (local / 24) * 32, tile, t);
  } else if (x < 6948) {
    if (e == 0) {
      int i = (x - 6912) * 256 + t;
      if (i < NEXP * QKVN) {
        int ee = i / QKVN, n = i % QKVN;
        float v = (n < HDIM) ? bq[ee * HDIM + n]
                : (n < 2 * HDIM) ? bk[ee * HDIM + n - HDIM]
                                 : bv[ee * HDIM + n - 2 * HDIM];
        bqkv[i] = v;
      }
    }
  } else {
    if (e == 0 && t == 0) {
      int n = 0;
      for (int ee = 0; ee < NEXP; ++ee)
        for (int b = 0; b < NB; ++b)
          if (eid[b] == ee) { order[n] = b; ord_eid[n] = ee; n++; }
    }
  }
}

// ---------------- MFMA GEMM: 3-stage pipelined K-loop -------------------------
// Single s_barrier per iter + fine vmcnt(4): prefetch for chunk it+2 stays in
// flight across the barrier (r7: vmcnt(0)-drain before barrier cost ~1 latency
// per iter — MfmaUtil 22%, VALUBusy 21%, both pipes idle). 3 stages make the
// slot being written (it+2) distinct from slots being read (it, it+1); the
// iter-it barrier separates the write from the last read at it-1.
template <int OUT_F16, int GELU, int KDIM, int SPLITK>
__global__ __launch_bounds__(256) void gemm_mfma(
    const _Float16* __restrict__ A, const _Float16* __restrict__ Wt,
    const float* __restrict__ Ball, const int* __restrict__ order,
    const int* __restrict__ ord_eid, void* __restrict__ Cv, int N) {
  constexpr int K = KDIM;
  constexpr int Kp = KDIM / SPLITK;
  constexpr int NIT = Kp / 32;
  int GX = N >> 7;
  int L = blockIdx.x;
  int low3 = L & 7, Mq = L >> 3;
  int x = Mq % GX, zhi = Mq / GX;
  int z = zhi * 8 + low3;
  int b = order[z];
  int e = ord_eid[z];
  int col0 = x * 128;
  int kz = blockIdx.y;
  int kbeg = kz * Kp;

  int t = threadIdx.x;
  int lane = t & 63, w = t >> 6;
  int quad = lane >> 4, l16 = lane & 15;
  int wr = (w >> 1) * 64, wc = (w & 1) * 64;

  __shared__ __align__(16) _Float16 As[3 * 128 * 32];
  __shared__ __align__(16) _Float16 Bs[3 * 128 * 32];

  const _Float16* Ab = A + (size_t)b * SEQ * K + kbeg;
  const _Float16* Wb = Wt + (size_t)e * N * K + (size_t)col0 * K + kbeg;

  int e0 = t * 8, e1 = 2048 + t * 8;
  int m0 = e0 >> 5, k0e = e0 & 31;
  int m1 = e1 >> 5, k1e = e1 & 31;
  const _Float16* ga0 = Ab + (size_t)m0 * K + k0e;
  const _Float16* ga1 = Ab + (size_t)m1 * K + k1e;
  const _Float16* gb0 = Wb + (size_t)m0 * K + k0e;
  const _Float16* gb1 = Wb + (size_t)m1 * K + k1e;

  auto issue = [&](int c, int st) {
    int off = c * 32;
    _Float16* Ast = As + st * 4096;
    _Float16* Bst = Bs + st * 4096;
    gld_lds16(ga0 + off, Ast + e0);
    gld_lds16(ga1 + off, Ast + e1);
    gld_lds16(gb0 + off, Bst + e0);
    gld_lds16(gb1 + off, Bst + e1);
  };

  f32x4 acc[4][4];
#pragma unroll
  for (int i = 0; i < 4; ++i)
#pragma unroll
    for (int j = 0; j < 4; ++j) acc[i][j] = (f32x4){0.f, 0.f, 0.f, 0.f};

  issue(0, 0);
  if (NIT > 1) issue(1, 1);

#pragma unroll
  for (int it = 0; it < NIT; ++it) {
    // wait own chunk-it loads: 2 chunks (8 ops) may be in flight -> vmcnt(4);
    // last iter has only chunk it outstanding -> vmcnt(0).
    if (it < NIT - 1) __builtin_amdgcn_s_waitcnt(0xF74);  // vmcnt(4), lgkm/exp untouched
    else              __builtin_amdgcn_s_waitcnt(0xF70);  // vmcnt(0)
    __builtin_amdgcn_s_barrier();

    int st = it % 3;
    const _Float16* Ast = As + st * 4096;
    const _Float16* Bst = Bs + st * 4096;
    f16x8 af[4], bf[4];
#pragma unroll
    for (int i = 0; i < 4; ++i)
      af[i] = *(const f16x8*)&Ast[(wr + i * 16 + l16) * 32 + quad * 8];
#pragma unroll
    for (int i = 0; i < 4; ++i)
      bf[i] = *(const f16x8*)&Bst[(wc + i * 16 + l16) * 32 + quad * 8];
#pragma unroll
    for (int i = 0; i < 4; ++i)
#pragma unroll
      for (int j = 0; j < 4; ++j)
        acc[i][j] = __builtin_amdgcn_mfma_f32_16x16x32_f16(af[i], bf[j], acc[i][j], 0, 0, 0);

    if (it + 2 < NIT) issue(it + 2, (it + 2) % 3);
  }

  const float* bias = Ball + (size_t)e * N;

  if (OUT_F16) {
    _Float16* Ch = (_Float16*)Cv + (size_t)b * SEQ * N;
#pragma unroll
    for (int i = 0; i < 4; ++i)
#pragma unroll
      for (int j = 0; j < 4; ++j) {
        int col = col0 + wc + j * 16 + l16;
        float bv = bias[col];
#pragma unroll
        for (int r = 0; r < 4; ++r) {
          int row = wr + i * 16 + quad * 4 + r;
          float v = acc[i][j][r] + bv;
          if (GELU) v = gelu_fast(v);
          Ch[(size_t)row * N + col] = (_Float16)v;
        }
      }
  } else {
    float* Cf = (float*)Cv + (size_t)kz * NB * SEQ * N + (size_t)b * SEQ * N;
    float bscale = (kz == 0) ? 1.f : 0.f;
#pragma unroll
    for (int i = 0; i < 4; ++i)
#pragma unroll
      for (int j = 0; j < 4; ++j) {
        int col = col0 + wc + j * 16 + l16;
        float bv = bias[col] * bscale;
#pragma unroll
        for (int r = 0; r < 4; ++r) {
          int row = wr + i * 16 + quad * 4 + r;
          Cf[(size_t)row * N + col] = acc[i][j][r] + bv;
        }
      }
  }
}

// ---------------- MFMA attention: one block per (head, sample) ----------------
__global__ __launch_bounds__(256) void attn_mfma(
    const _Float16* __restrict__ QKV, const float* __restrict__ mask,
    _Float16* __restrict__ Ctx) {
  int h = blockIdx.x, b = blockIdx.y;
  int t = threadIdx.x;
  int w = t >> 6, lane = t & 63, quad = lane >> 4, l16 = lane & 15;

  __shared__ __align__(16) char smem[54784];
  _Float16* Qs = (_Float16*)smem;                 // [128][72]
  _Float16* Ks = (_Float16*)(smem + 18432);       // [128][72]
  _Float16* Ps = (_Float16*)smem;                 // [128][136]
  _Float16* Vt = (_Float16*)(smem + 36864);       // [64][136]
  float* mrow = (float*)(smem + 54272);           // [128]

  const _Float16* Qb = QKV + (size_t)b * SEQ * QKVN + h * HEADD;
  const _Float16* Kb = Qb + HDIM;
  const _Float16* Vb = Qb + 2 * HDIM;

#pragma unroll
  for (int it = 0; it < 4; ++it) {
    int chunk = t + it * 256;
    int row = chunk >> 3, c = chunk & 7;
    *(f16x8*)&Qs[row * 72 + c * 8] = *(const f16x8*)(Qb + (size_t)row * QKVN + c * 8);
    *(f16x8*)&Ks[row * 72 + c * 8] = *(const f16x8*)(Kb + (size_t)row * QKVN + c * 8);
  }
  {
    int vc = t & 7, vjp0 = t >> 3;
#pragma unroll
    for (int it = 0; it < 2; ++it) {
      int jp = vjp0 + it * 32;
      f16x8 v0 = *(const f16x8*)(Vb + (size_t)(2 * jp) * QKVN + vc * 8);
      f16x8 v1 = *(const f16x8*)(Vb + (size_t)(2 * jp + 1) * QKVN + vc * 8);
#pragma unroll
      for (int i = 0; i < 8; ++i) {
        int d = vc * 8 + i;
        unsigned ua = __builtin_bit_cast(unsigned short, (_Float16)v0[i]);
        unsigned ub = __builtin_bit_cast(unsigned short, (_Float16)v1[i]);
        ((unsigned*)Vt)[d * 68 + jp] = ua | (ub << 16);
      }
    }
  }
  if (t < SEQ) mrow[t] = mask[(size_t)b * SEQ + t];
  __syncthreads();

  int m0 = w * 32;
  f32x4 accs[2][8];
#pragma unroll
  for (int i = 0; i < 2; ++i)
#pragma unroll
    for (int j = 0; j < 8; ++j) accs[i][j] = (f32x4){0.f, 0.f, 0.f, 0.f};

#pragma unroll
  for (int ks = 0; ks < 2; ++ks) {
    int k0 = ks * 32 + quad * 8;
    f16x8 af[2], bf[8];
#pragma unroll
    for (int i = 0; i < 2; ++i)
      af[i] = *(const f16x8*)&Qs[(m0 + i * 16 + l16) * 72 + k0];
#pragma unroll
    for (int j = 0; j < 8; ++j)
      bf[j] = *(const f16x8*)&Ks[(j * 16 + l16) * 72 + k0];
#pragma unroll
    for (int i = 0; i < 2; ++i)
#pragma unroll
      for (int j = 0; j < 8; ++j)
        accs[i][j] = __builtin_amdgcn_mfma_f32_16x16x32_f16(af[i], bf[j], accs[i][j], 0, 0, 0);
  }
  __syncthreads();

  float mv[8];
#pragma unroll
  for (int j = 0; j < 8; ++j) mv[j] = mrow[j * 16 + l16];

  float linv[2][4];
#pragma unroll
  for (int i = 0; i < 2; ++i) {
#pragma unroll
    for (int j = 0; j < 8; ++j)
#pragma unroll
      for (int r = 0; r < 4; ++r)
        accs[i][j][r] = accs[i][j][r] * 0.125f + mv[j];
#pragma unroll
    for (int r = 0; r < 4; ++r) {
      float m = accs[i][0][r];
#pragma unroll
      for (int j = 1; j < 8; ++j) m = fmaxf(m, accs[i][j][r]);
      m = fmaxf(m, __shfl_xor(m, 1));
      m = fmaxf(m, __shfl_xor(m, 2));
      m = fmaxf(m, __shfl_xor(m, 4));
      m = fmaxf(m, __shfl_xor(m, 8));
      float sum = 0.f;
#pragma unroll
      for (int j = 0; j < 8; ++j) {
        float p = __expf(accs[i][j][r] - m);
        accs[i][j][r] = p;
        sum += p;
      }
      sum += __shfl_xor(sum, 1);
      sum += __shfl_xor(sum, 2);
      sum += __shfl_xor(sum, 4);
      sum += __shfl_xor(sum, 8);
      linv[i][r] = 1.f / sum;
    }
    int rowb = m0 + i * 16 + quad * 4;
#pragma unroll
    for (int j = 0; j < 8; ++j)
#pragma unroll
      for (int r = 0; r < 4; ++r)
        Ps[(rowb + r) * 136 + j * 16 + l16] = (_Float16)accs[i][j][r];
  }
  __syncthreads();

  f32x4 acco[2][4];
#pragma unroll
  for (int i = 0; i < 2; ++i)
#pragma unroll
    for (int j = 0; j < 4; ++j) acco[i][j] = (f32x4){0.f, 0.f, 0.f, 0.f};

#pragma unroll
  for (int ks = 0; ks < 4; ++ks) {
    int k0 = ks * 32 + quad * 8;
    f16x8 pa[2], vf[4];
#pragma unroll
    for (int i = 0; i < 2; ++i)
      pa[i] = *(const f16x8*)&Ps[(m0 + i * 16 + l16) * 136 + k0];
#pragma unroll
    for (int j = 0; j < 4; ++j)
      vf[j] = *(const f16x8*)&Vt[(j * 16 + l16) * 136 + k0];
#pragma unroll
    for (int i = 0; i < 2; ++i)
#pragma unroll
      for (int j = 0; j < 4; ++j)
        acco[i][j] = __builtin_amdgcn_mfma_f32_16x16x32_f16(pa[i], vf[j], acco[i][j], 0, 0, 0);
  }

  _Float16* Cb = Ctx + (size_t)b * SEQ * HDIM + h * HEADD;
#pragma unroll
  for (int i = 0; i < 2; ++i)
#pragma unroll
    for (int j = 0; j < 4; ++j)
#pragma unroll
      for (int r = 0; r < 4; ++r) {
        int row = m0 + i * 16 + quad * 4 + r;
        int d = j * 16 + l16;
        Cb[(size_t)row * HDIM + d] = (_Float16)(acco[i][j][r] * linv[i][r]);
      }
}

// ---------------- residual + NP partials + layernorm ---------------------------
template <int NP>
__global__ __launch_bounds__(256) void resid_ln_kernel(
    const float* __restrict__ X, const float* __restrict__ P0,
    const float* __restrict__ P1,
    const float* __restrict__ Gall, const float* __restrict__ Ball,
    const int* __restrict__ eid, float* __restrict__ Out,
    _Float16* __restrict__ Out16) {
  int row = blockIdx.x, b = blockIdx.y, t = threadIdx.x;
  int e = eid[b];
  size_t off = ((size_t)b * SEQ + row) * HDIM;
  const float* x = X + off;
  const float* p0 = P0 + off;
  const float* p1 = (NP > 1) ? P1 + off : nullptr;
  float* o = Out + off;
  const float* g = Gall + (size_t)e * HDIM;
  const float* bb = Ball + (size_t)e * HDIM;

  __shared__ float buf[HDIM];
  __shared__ float red[256];

  float s = 0.f;
  for (int h = t; h < HDIM; h += 256) {
    float v = x[h] + p0[h];
    if (NP > 1) v += p1[h];
    buf[h] = v;
    s += v;
  }
  red[t] = s;
  __syncthreads();
  for (int off2 = 128; off2 > 0; off2 >>= 1) {
    if (t < off2) red[t] += red[t + off2];
    __syncthreads();
  }
  float mean = red[0] * (1.0f / HDIM);
  __syncthreads();

  float s2 = 0.f;
  for (int h = t; h < HDIM; h += 256) {
    float d = buf[h] - mean;
    s2 += d * d;
  }
  red[t] = s2;
  __syncthreads();
  for (int off2 = 128; off2 > 0; off2 >>= 1) {
    if (t < off2) red[t] += red[t + off2];
    __syncthreads();
  }
  float var = red[0] * (1.0f / HDIM);
  float rs = rsqrtf(var + 1e-12f);

  for (int h = t; h < HDIM; h += 256) {
    float v = (buf[h] - mean) * rs * g[h] + bb[h];
    o[h] = v;
    if (Out16) Out16[off + h] = (_Float16)v;
  }
}

// ------------------------------------------------------------------------------
extern "C" void kernel_launch(void* const* d_in, const int* in_sizes, int n_in,
                              void* d_out, int out_size, void* d_ws, size_t ws_size,
                              hipStream_t stream) {
  const float* hs   = (const float*)d_in[0];
  const float* mask = (const float*)d_in[1];
  const float* cen  = (const float*)d_in[2];
  const float* wq = (const float*)d_in[3];
  const float* wk = (const float*)d_in[4];
  const float* wv = (const float*)d_in[5];
  const float* wo = (const float*)d_in[6];
  const float* bq = (const float*)d_in[7];
  const float* bk = (const float*)d_in[8];
  const float* bv = (const float*)d_in[9];
  const float* bo = (const float*)d_in[10];
  const float* ln1g = (const float*)d_in[11];
  const float* ln1b = (const float*)d_in[12];
  const float* w1 = (const float*)d_in[13];
  const float* b1 = (const float*)d_in[14];
  const float* w2 = (const float*)d_in[15];
  const float* b2 = (const float*)d_in[16];
  const float* ln2g = (const float*)d_in[17];
  const float* ln2b = (const float*)d_in[18];
  float* out = (float*)d_out;

  const size_t sh = (size_t)SEQ * HDIM;

  char* p = (char*)d_ws;
  int* eid = (int*)p;                 p += 256;
  int* order = (int*)p;               p += 256;
  int* ord_eid = (int*)p;             p += 256;
  float* bqkv = (float*)p;            p += (size_t)NEXP * QKVN * 4;
  _Float16* Wqkvt = (_Float16*)p;     p += (size_t)NEXP * QKVN * HDIM * 2;
  _Float16* Wot = (_Float16*)p;       p += (size_t)NEXP * HDIM * HDIM * 2;
  _Float16* W1t = (_Float16*)p;       p += (size_t)NEXP * FFDIM * HDIM * 2;
  _Float16* W2t = (_Float16*)p;       p += (size_t)NEXP * HDIM * FFDIM * 2;
  _Float16* x16 = (_Float16*)p;       p += (size_t)NB * sh * 2;

  char* region = p;                   p += (size_t)NB * SEQ * QKVN * 2;
  _Float16* ctx16 = (_Float16*)p;     p += (size_t)NB * sh * 2;
  float* aof = (float*)p;             p += (size_t)NB * sh * 4;
  _Float16* ao16 = (_Float16*)p;      p += (size_t)NB * sh * 2;
  char* ffreg = p;                    p += (size_t)NB * SEQ * FFDIM * 2;

  float* woparts = (float*)ffreg;
  float* w2parts = (float*)region;
  _Float16* ff16 = (_Float16*)ffreg;

  // 1. routing + hs->f16
  route_cvt_kernel<<<NB, 256, 0, stream>>>(hs, cen, eid, x16);
  // 2. weight prep (single launch)
  prep_weights<<<dim3(6949, NEXP), 256, 0, stream>>>(
      wq, wk, wv, wo, w1, w2, bq, bk, bv,
      Wqkvt, Wot, W1t, W2t, bqkv, eid, order, ord_eid);
  // 3. QKV fused -> region (f16)
  gemm_mfma<1, 0, HDIM, 1><<<dim3((QKVN / 128) * NB, 1), 256, 0, stream>>>(
      x16, Wqkvt, bqkv, order, ord_eid, region, QKVN);
  // 4. attention -> ctx16
  attn_mfma<<<dim3(NHEAD, NB), 256, 0, stream>>>(
      (const _Float16*)region, mask, ctx16);
  // 5. wo split-K=2 -> woparts (ffreg)
  gemm_mfma<0, 0, HDIM, 2><<<dim3((HDIM / 128) * NB, 2), 256, 0, stream>>>(
      ctx16, Wot, bo, order, ord_eid, woparts, HDIM);
  // 6. LN1
  resid_ln_kernel<2><<<dim3(SEQ, NB), 256, 0, stream>>>(
      hs, woparts, woparts + (size_t)NB * sh, ln1g, ln1b, eid, aof, ao16);
  // 7. w1 + fast GELU -> ff16
  gemm_mfma<1, 1, HDIM, 1><<<dim3((FFDIM / 128) * NB, 1), 256, 0, stream>>>(
      ao16, W1t, b1, order, ord_eid, ff16, FFDIM);
  // 8. w2 split-K=2 -> w2parts
  gemm_mfma<0, 0, FFDIM, 2><<<dim3((HDIM / 128) * NB, 2), 256, 0, stream>>>(
      ff16, W2t, b2, order, ord_eid, w2parts, HDIM);
  // 9. LN2 -> out
  resid_ln_kernel<2><<<dim3(SEQ, NB), 256, 0, stream>>>(
      aof, w2parts, w2parts + (size_t)NB * sh, ln2g, ln2b, eid, out,
      (_Float16*)nullptr);
}